// Round 8
// baseline (140.322 us; speedup 1.0000x reference)
//
#include <hip/hip_runtime.h>
#include <cstdint>
#include <type_traits>

// GPT MHA forward. B=2, T=2048, C=1024, H=16, d=64.
// cast x->bf16 | transpose weights (wq pre-scaled 0.125*log2e) | bias concat
// | QKV GEMM (gload_lds, XCD swizzle) | V-transpose | causal flash attn
//   (32x32 MFMA, 4 waves x 32 q-rows, in-register P via cvt_pk+permlane32_swap,
//    XOR-swizzled K/V LDS, swapped QK^T, exp2 softmax, defer-max, async-STAGE,
//    bh->XCD pinning, masked-tile skip) | out-proj GEMM.

#define TSEQ  2048
#define BATCH 2
#define CDIM  1024
#define NHEAD 16
#define DHEAD 64
#define NROWS (BATCH * TSEQ)  // 4096

// 0.125 (1/sqrt(d)) * log2(e): folded into wq/bq so softmax uses exp2
#define QSCALE 0.1803368801111244f

typedef unsigned short u16;
typedef u16   u16x8  __attribute__((ext_vector_type(8)));
typedef __bf16 bf16x8 __attribute__((ext_vector_type(8)));
typedef __bf16 bf16x2 __attribute__((ext_vector_type(2)));
typedef float f32x4  __attribute__((ext_vector_type(4)));
typedef float f32x16 __attribute__((ext_vector_type(16)));
typedef uint32_t u32x4 __attribute__((ext_vector_type(4)));

typedef const __attribute__((address_space(1))) void* gas_vp;
typedef __attribute__((address_space(3))) void* las_vp;

__device__ __forceinline__ u16 f2bf(float f) {
  return __builtin_bit_cast(u16, (__bf16)f);
}

__device__ __forceinline__ uint32_t pack2bf(float a, float b) {
  bf16x2 v;
  v[0] = (__bf16)a;
  v[1] = (__bf16)b;
  return __builtin_bit_cast(uint32_t, v);
}

__device__ __forceinline__ f32x4 mfma_bf16(u16x8 a, u16x8 b, f32x4 c) {
  return __builtin_amdgcn_mfma_f32_16x16x32_bf16(
      __builtin_bit_cast(bf16x8, a), __builtin_bit_cast(bf16x8, b), c, 0, 0, 0);
}

__device__ __forceinline__ f32x16 mfma32(u16x8 a, u16x8 b, f32x16 c) {
  return __builtin_amdgcn_mfma_f32_32x32x16_bf16(
      __builtin_bit_cast(bf16x8, a), __builtin_bit_cast(bf16x8, b), c, 0, 0, 0);
}

// v_permlane32_swap_b32: a' = [a.lo | b.lo], b' = [a.hi | b.hi] (halves swap)
__device__ __forceinline__ void perm32swap(uint32_t& a, uint32_t& b) {
  asm volatile("v_permlane32_swap_b32 %0, %1" : "+v"(a), "+v"(b));
}

__device__ __forceinline__ void gload16(const u16* g, u16* l) {
  __builtin_amdgcn_global_load_lds((gas_vp)g, (las_vp)l, 16, 0, 0);
}

// ---------------- prep kernels ----------------

__global__ __launch_bounds__(256) void cast_x_kernel(const float* __restrict__ in,
                                                     u16* __restrict__ out, int n4) {
  int i = blockIdx.x * 256 + threadIdx.x;
  if (i < n4) {
    float4 v = ((const float4*)in)[i];
    ((uint2*)out)[i] = make_uint2(pack2bf(v.x, v.y), pack2bf(v.z, v.w));
  }
}

__global__ __launch_bounds__(256) void transpose_cast_kernel(
    const float* __restrict__ w0, const float* __restrict__ w1,
    const float* __restrict__ w2, const float* __restrict__ w3,
    u16* __restrict__ outQKV, u16* __restrict__ outO) {
  __shared__ float tile[32][33];
  const int m = blockIdx.z;
  const float* w = (m == 0) ? w0 : (m == 1) ? w1 : (m == 2) ? w2 : w3;
  const float scale = (m == 0) ? QSCALE : 1.0f;
  u16* out = (m < 3) ? (outQKV + (size_t)m * CDIM * CDIM) : outO;
  const int n0 = blockIdx.x * 32;
  const int k0 = blockIdx.y * 32;
  const int tx = threadIdx.x, ty = threadIdx.y;  // block (32, 8)
#pragma unroll
  for (int i = 0; i < 4; ++i)
    tile[ty + i * 8][tx] = w[(size_t)(k0 + ty + i * 8) * CDIM + n0 + tx];
  __syncthreads();
#pragma unroll
  for (int i = 0; i < 4; ++i)
    out[(size_t)(n0 + ty + i * 8) * CDIM + k0 + tx] = f2bf(tile[tx][ty + i * 8] * scale);
}

__global__ __launch_bounds__(256) void bias_concat_kernel(const float* __restrict__ bq,
                                                          const float* __restrict__ bk,
                                                          const float* __restrict__ bv,
                                                          float* __restrict__ out) {
  int i = blockIdx.x * 256 + threadIdx.x;
  if (i < 3 * CDIM) {
    float v = (i < CDIM) ? bq[i] * QSCALE
            : (i < 2 * CDIM) ? bk[i - CDIM] : bv[i - 2 * CDIM];
    out[i] = v;
  }
}

// V part of QKV [B*T][3C] -> Vt [B][H][D][T]
__global__ __launch_bounds__(256) void vtrans_kernel(const u16* __restrict__ QKV,
                                                     u16* __restrict__ Vt) {
  __shared__ u16 tile[32][33];
  const int bh = blockIdx.z;
  const int b = bh >> 4, h = bh & 15;
  const int t0 = blockIdx.x * 32, d0 = blockIdx.y * 32;
  const int tx = threadIdx.x, ty = threadIdx.y;  // block (32, 8)
#pragma unroll
  for (int i = 0; i < 4; ++i)
    tile[ty + i * 8][tx] =
        QKV[(size_t)(b * TSEQ + t0 + ty + i * 8) * (3 * CDIM) + 2 * CDIM + h * DHEAD + d0 + tx];
  __syncthreads();
#pragma unroll
  for (int i = 0; i < 4; ++i)
    Vt[(size_t)((b * NHEAD + h) * DHEAD + d0 + ty + i * 8) * TSEQ + t0 + tx] =
        tile[tx][ty + i * 8];
}

// ---------------- GEMM: C[M][N] = A[M][K] @ Bt[N][K]^T + bias ----------------
// 128x128 tile, BK=32, 4 waves, global_load_lds staging; 1D grid + XCD swizzle.

template <typename OutT>
__global__ __launch_bounds__(256) void gemm_bt_kernel(
    const u16* __restrict__ A, const u16* __restrict__ Bt,
    const float* __restrict__ bias, OutT* __restrict__ C,
    int M, int N, int K, int mblocks) {
  __shared__ u16 As[128 * 32];
  __shared__ u16 Bs[128 * 32];
  const int nwg = gridDim.x;
  const int lid = blockIdx.x;
  const int swz = (lid & 7) * (nwg >> 3) + (lid >> 3);
  const int m0 = (swz % mblocks) * 128;
  const int n0 = (swz / mblocks) * 128;

  const int t = threadIdx.x;
  const int lane = t & 63;
  const int w = t >> 6;
  const int wr = w >> 1, wc = w & 1;
  const int l15 = lane & 15;
  const int lg = lane >> 4;
  const int srow = lane >> 2;
  const int scol = (lane & 3) * 8;

  f32x4 acc[4][4];
#pragma unroll
  for (int i = 0; i < 4; ++i)
#pragma unroll
    for (int j = 0; j < 4; ++j) acc[i][j] = f32x4{0.f, 0.f, 0.f, 0.f};

  for (int k0 = 0; k0 < K; k0 += 32) {
    __syncthreads();
#pragma unroll
    for (int ci = 0; ci < 2; ++ci) {
      const int chunk = w * 2 + ci;
      const int grow = chunk * 16 + srow;
      gload16(&A[(size_t)(m0 + grow) * K + k0 + scol], &As[chunk * 512]);
      gload16(&Bt[(size_t)(n0 + grow) * K + k0 + scol], &Bs[chunk * 512]);
    }
    __syncthreads();
    u16x8 af[4], bf[4];
#pragma unroll
    for (int i = 0; i < 4; ++i)
      af[i] = *(const u16x8*)(&As[(wr * 64 + i * 16 + l15) * 32 + lg * 8]);
#pragma unroll
    for (int j = 0; j < 4; ++j)
      bf[j] = *(const u16x8*)(&Bs[(wc * 64 + j * 16 + l15) * 32 + lg * 8]);
#pragma unroll
    for (int i = 0; i < 4; ++i)
#pragma unroll
      for (int j = 0; j < 4; ++j) acc[i][j] = mfma_bf16(af[i], bf[j], acc[i][j]);
  }

#pragma unroll
  for (int j = 0; j < 4; ++j) {
    int col = n0 + wc * 64 + j * 16 + l15;
    float bv = bias[col];
#pragma unroll
    for (int i = 0; i < 4; ++i) {
#pragma unroll
      for (int r = 0; r < 4; ++r) {
        int row = m0 + wr * 64 + i * 16 + lg * 4 + r;
        float val = acc[i][j][r] + bv;
        if constexpr (std::is_same<OutT, float>::value)
          C[(size_t)row * N + col] = val;
        else
          C[(size_t)row * N + col] = f2bf(val);
      }
    }
  }
}

// ---------------- causal flash attention (32x32 MFMA, in-register P) --------
// 512 blocks x 4 waves x 32 q-rows (128 q-rows/block); KVBLK=64 staged in
// XOR-swizzled LDS. Swapped QK^T via mfma_32x32x16: lane holds S^T[.][q=lane&31];
// full P-row lives in {lane, lane^32} -> PV B-frags built in registers with
// cvt_pk + v_permlane32_swap_b32 (no P LDS traffic). bh->XCD pinning + LPT.
// A-operand layout: row=lane&31, k=(lane>>5)*8+e. C/D: col=lane&31,
// row=(reg&3)+8*(reg>>2)+4*(lane>>5) [m74/m101 verified].

__global__ __launch_bounds__(256) void attn_kernel(const u16* __restrict__ QKV,
                                                   const u16* __restrict__ Vt,
                                                   u16* __restrict__ O) {
  __shared__ u16 KV[2][64 * 64];  // Ks, Vs (8KB each); epilogue: 4x4KB O staging
  char* KsB = (char*)KV[0];
  char* VsB = (char*)KV[1];

  const int t = threadIdx.x;
  const int lane = t & 63;
  const int w = t >> 6;             // 0..3
  const int l31 = lane & 31;
  const int hi = lane >> 5;         // 0/1
  const int xorv = (l31 & 7) << 4;

  // bh->XCD pinning + LPT (identical to R7 decode)
  const int lid = blockIdx.x;       // 0..511
  const int xcd = lid & 7;
  const int m = lid >> 3;           // 0..63
  const int bh = (m & 3) * 8 + xcd; // 0..31
  const int qb = 15 - (m >> 2);     // 0..15, heavy first
  const int b = bh >> 4, h = bh & 15;
  const int q0w = qb * 128 + w * 32;  // wave's 32 q-rows
  const int nkt = (qb + 1) * 2;       // k-tiles of 64 (block-uniform)

  const size_t RS = 3 * CDIM;
  const u16* Qp  = QKV + (size_t)(b * TSEQ) * RS + h * DHEAD;
  const u16* Kp  = Qp + CDIM;
  const u16* Vgp = Vt + (size_t)(b * NHEAD + h) * DHEAD * TSEQ;

  // Q frags (B-operand): Q[q0w + l31][c*16 + hi*8 + 0..7], c = contraction slice
  u16x8 qf[4];
#pragma unroll
  for (int c = 0; c < 4; ++c)
    qf[c] = *(const u16x8*)(&Qp[(size_t)(q0w + l31) * RS + c * 16 + hi * 8]);

  f32x16 acc0, acc1;  // O^T tiles: d = dt*32 + crow(r,hi), q = q0w + l31
#pragma unroll
  for (int i = 0; i < 16; ++i) { acc0[i] = 0.f; acc1[i] = 0.f; }
  float m_run = -3e38f, l_run = 0.f;

  // staging: 256 threads, rows sr (0..63), 2x16B chunks at u16 col sc0, sc0+8
  const int sr = t >> 2;
  const int sc0 = (t & 3) * 16;
  const int swb0 = sr * 128 + ((sc0 * 2) ^ ((sr & 7) << 4));
  const int swb1 = sr * 128 + ((sc0 * 2 + 16) ^ ((sr & 7) << 4));

  // T14 prologue: first K/V tile -> regs
  u16x8 kreg0 = *(const u16x8*)(&Kp[(size_t)sr * RS + sc0]);
  u16x8 kreg1 = *(const u16x8*)(&Kp[(size_t)sr * RS + sc0 + 8]);
  u16x8 vreg0 = *(const u16x8*)(&Vgp[(size_t)sr * TSEQ + sc0]);
  u16x8 vreg1 = *(const u16x8*)(&Vgp[(size_t)sr * TSEQ + sc0 + 8]);

  for (int kb = 0; kb < nkt; ++kb) {
    __syncthreads();
    *(u16x8*)(KsB + swb0) = kreg0;
    *(u16x8*)(KsB + swb1) = kreg1;
    *(u16x8*)(VsB + swb0) = vreg0;
    *(u16x8*)(VsB + swb1) = vreg1;
    __syncthreads();

    if (kb + 1 < nkt) {  // async-STAGE: next tile -> regs, hides under compute
      kreg0 = *(const u16x8*)(&Kp[(size_t)((kb + 1) * 64 + sr) * RS + sc0]);
      kreg1 = *(const u16x8*)(&Kp[(size_t)((kb + 1) * 64 + sr) * RS + sc0 + 8]);
      vreg0 = *(const u16x8*)(&Vgp[(size_t)sr * TSEQ + (kb + 1) * 64 + sc0]);
      vreg1 = *(const u16x8*)(&Vgp[(size_t)sr * TSEQ + (kb + 1) * 64 + sc0 + 8]);
    }

    if (kb * 64 > q0w + 31) continue;  // fully-masked tile: stage+barrier only

    // S^T = mfma(K, Q): s0 = k-rows kb*64+crow, s1 = kb*64+32+crow; col q
    f32x16 s0, s1;
#pragma unroll
    for (int i = 0; i < 16; ++i) { s0[i] = 0.f; s1[i] = 0.f; }
    __builtin_amdgcn_s_setprio(1);
#pragma unroll
    for (int c = 0; c < 4; ++c) {
      const int boff = (c * 32 + hi * 16) ^ xorv;
      u16x8 ka = *(const u16x8*)(KsB + l31 * 128 + boff);
      u16x8 kc = *(const u16x8*)(KsB + (32 + l31) * 128 + boff);
      s0 = mfma32(ka, qf[c], s0);
      s1 = mfma32(kc, qf[c], s1);
    }
    __builtin_amdgcn_s_setprio(0);

    if (kb * 64 + 63 > q0w) {  // causal mask (wave-uniform predicate)
      const int q_abs = q0w + l31;
#pragma unroll
      for (int r = 0; r < 16; ++r) {
        const int crow = (r & 3) + 8 * (r >> 2) + 4 * hi;
        if (kb * 64 + crow > q_abs) s0[r] = -1e9f;
        if (kb * 64 + 32 + crow > q_abs) s1[r] = -1e9f;
      }
    }

    // in-lane max over 32 vals (all same q); vote gates rescale (T13, THR=8)
    float mx = s0[0];
#pragma unroll
    for (int r = 0; r < 16; ++r) { mx = fmaxf(mx, s0[r]); mx = fmaxf(mx, s1[r]); }
    if (__any(mx > m_run + 8.f)) {
      float gm = fmaxf(mx, __shfl_xor(mx, 32));
      float mnew = fmaxf(m_run, gm);
      float fac = exp2f(m_run - mnew);
      m_run = mnew;
      l_run *= fac;
#pragma unroll
      for (int i = 0; i < 16; ++i) { acc0[i] *= fac; acc1[i] *= fac; }
    }

    // P = exp2(S - m), packed to bf16 pairs per k-tile (P2a: k<32, P2b: k>=32)
    uint32_t P2a[8], P2b[8];
    float ls = 0.f;
#pragma unroll
    for (int j = 0; j < 8; ++j) {
      float p0 = exp2f(s0[2 * j] - m_run);
      float p1 = exp2f(s0[2 * j + 1] - m_run);
      float p2 = exp2f(s1[2 * j] - m_run);
      float p3 = exp2f(s1[2 * j + 1] - m_run);
      ls += (p0 + p1) + (p2 + p3);
      P2a[j] = pack2bf(p0, p1);
      P2b[j] = pack2bf(p2, p3);
    }
    l_run += ls;

    // PV B-frags in-register: swap(a,b) -> a'=[a.lo|b.lo]=word(hi-run lo),
    // b'=[a.hi|b.hi]=word(hi-run hi). frag(ks) covers k=ks*16+hi*8+0..7.
    u16x8 pf0, pf1, pf2, pf3;
    {
      uint32_t a0 = P2a[0], b0 = P2a[2], a1 = P2a[1], b1 = P2a[3];
      perm32swap(a0, b0);
      perm32swap(a1, b1);
      pf0 = __builtin_bit_cast(u16x8, u32x4{a0, a1, b0, b1});
      uint32_t c0 = P2a[4], d0 = P2a[6], c1 = P2a[5], d1 = P2a[7];
      perm32swap(c0, d0);
      perm32swap(c1, d1);
      pf1 = __builtin_bit_cast(u16x8, u32x4{c0, c1, d0, d1});
      uint32_t e0 = P2b[0], f0 = P2b[2], e1 = P2b[1], f1 = P2b[3];
      perm32swap(e0, f0);
      perm32swap(e1, f1);
      pf2 = __builtin_bit_cast(u16x8, u32x4{e0, e1, f0, f1});
      uint32_t g0 = P2b[4], h0 = P2b[6], g1 = P2b[5], h1 = P2b[7];
      perm32swap(g0, h0);
      perm32swap(g1, h1);
      pf3 = __builtin_bit_cast(u16x8, u32x4{g0, g1, h0, h1});
    }

    // O^T += mfma(V^T, P): acc0 = d 0..31, acc1 = d 32..63
    __builtin_amdgcn_s_setprio(1);
#pragma unroll
    for (int ks = 0; ks < 4; ++ks) {
      const int boff = (ks * 32 + hi * 16) ^ xorv;
      u16x8 va = *(const u16x8*)(VsB + l31 * 128 + boff);
      u16x8 vb = *(const u16x8*)(VsB + (32 + l31) * 128 + boff);
      u16x8 pf = (ks == 0) ? pf0 : (ks == 1) ? pf1 : (ks == 2) ? pf2 : pf3;
      acc0 = mfma32(va, pf, acc0);
      acc1 = mfma32(vb, pf, acc1);
    }
    __builtin_amdgcn_s_setprio(0);
  }

  __syncthreads();  // all waves done with Ks/Vs before O-staging reuse

  // epilogue: l across the 2 lanes per q, normalize, un-transpose via LDS
  float lt = l_run + __shfl_xor(l_run, 32);
  float inv = 1.f / lt;
  char* ob = (char*)KV[0] + w * 4096;  // wave-private 4KB: [q 0..31][d 0..63]
#pragma unroll
  for (int j = 0; j < 8; ++j) {
    const int d0 = ((2 * j) & 3) + 8 * (j >> 1) + 4 * hi;  // crow(2j); even
    uint32_t pa = pack2bf(acc0[2 * j] * inv, acc0[2 * j + 1] * inv);
    uint32_t pb = pack2bf(acc1[2 * j] * inv, acc1[2 * j + 1] * inv);
    *(uint32_t*)(ob + l31 * 128 + ((d0 * 2) ^ ((l31 & 7) << 4))) = pa;
    *(uint32_t*)(ob + l31 * 128 + (((32 + d0) * 2) ^ ((l31 & 7) << 4))) = pb;
  }
#pragma unroll
  for (int i = 0; i < 4; ++i) {
    const int rl = i * 8 + (lane >> 3);  // 0..31
    const int ch = lane & 7;
    u16x8 vv = *(const u16x8*)(ob + rl * 128 + ((ch * 16) ^ ((rl & 7) << 4)));
    *(u16x8*)(&O[(size_t)(b * TSEQ + q0w + rl) * CDIM + h * DHEAD + ch * 8]) = vv;
  }
}

// ---------------- launch ----------------

extern "C" void kernel_launch(void* const* d_in, const int* in_sizes, int n_in,
                              void* d_out, int out_size, void* d_ws, size_t ws_size,
                              hipStream_t stream) {
  const float* x  = (const float*)d_in[0];
  const float* wq = (const float*)d_in[1];
  const float* bq = (const float*)d_in[2];
  const float* wk = (const float*)d_in[3];
  const float* bk = (const float*)d_in[4];
  const float* wv = (const float*)d_in[5];
  const float* bv = (const float*)d_in[6];
  const float* wo = (const float*)d_in[7];
  const float* bo = (const float*)d_in[8];
  float* out = (float*)d_out;

  char* ws = (char*)d_ws;
  u16*  xb      = (u16*)(ws);                 // 8MB; dead after QKV GEMM
  u16*  Vtg     = (u16*)(ws);                 // aliases xb (written after)
  u16*  wqkvT   = (u16*)(ws + (8ll << 20));
  u16*  woT     = (u16*)(ws + (14ll << 20));
  u16*  QKV     = (u16*)(ws + (16ll << 20));
  u16*  Obuf    = (u16*)(ws + (40ll << 20));
  float* biasqkv = (float*)(ws + (48ll << 20));

  cast_x_kernel<<<(NROWS * CDIM / 4 + 255) / 256, 256, 0, stream>>>(x, xb, NROWS * CDIM / 4);
  {
    dim3 g(CDIM / 32, CDIM / 32, 4), blk(32, 8);
    transpose_cast_kernel<<<g, blk, 0, stream>>>(wq, wk, wv, wo, wqkvT, woT);
  }
  bias_concat_kernel<<<12, 256, 0, stream>>>(bq, bk, bv, biasqkv);
  gemm_bt_kernel<u16><<<(NROWS / 128) * ((3 * CDIM) / 128), 256, 0, stream>>>(
      xb, wqkvT, biasqkv, QKV, NROWS, 3 * CDIM, CDIM, NROWS / 128);
  {
    dim3 g(TSEQ / 32, DHEAD / 32, BATCH * NHEAD), blk(32, 8);
    vtrans_kernel<<<g, blk, 0, stream>>>(QKV, Vtg);
  }
  attn_kernel<<<512, 256, 0, stream>>>(QKV, Vtg, Obuf);
  gemm_bt_kernel<float><<<(NROWS / 128) * (CDIM / 128), 256, 0, stream>>>(
      Obuf, woT, bo, out, NROWS, CDIM, CDIM, NROWS / 128);
}

// Round 9
// 135.989 us; speedup vs baseline: 1.0319x; 1.0319x over previous
//
#include <hip/hip_runtime.h>
#include <cstdint>
#include <type_traits>

// GPT MHA forward. B=2, T=2048, C=1024, H=16, d=64.
// cast x->bf16 | transpose weights (wq pre-scaled 0.125*log2e) | bias concat
// | QKV GEMM (BK=64, gload_lds w/ pre-swizzled source, T2 read swizzle, XCD)
// | V-transpose | causal flash attn (8 waves x 16 q-rows, double-buffered K/V,
//   ONE barrier per k-tile, XOR-swizzled LDS, swapped QK^T, exp2 softmax,
//   defer-max, async-STAGE, bh->XCD pinning, masked-tile skip) | out-proj GEMM.

#define TSEQ  2048
#define BATCH 2
#define CDIM  1024
#define NHEAD 16
#define DHEAD 64
#define NROWS (BATCH * TSEQ)  // 4096

// 0.125 (1/sqrt(d)) * log2(e): folded into wq/bq so softmax uses exp2
#define QSCALE 0.1803368801111244f

typedef unsigned short u16;
typedef u16   u16x8  __attribute__((ext_vector_type(8)));
typedef __bf16 bf16x8 __attribute__((ext_vector_type(8)));
typedef __bf16 bf16x2 __attribute__((ext_vector_type(2)));
typedef float f32x4  __attribute__((ext_vector_type(4)));

typedef const __attribute__((address_space(1))) void* gas_vp;
typedef __attribute__((address_space(3))) void* las_vp;

__device__ __forceinline__ u16 f2bf(float f) {
  return __builtin_bit_cast(u16, (__bf16)f);
}

__device__ __forceinline__ uint32_t pack2bf(float a, float b) {
  bf16x2 v;
  v[0] = (__bf16)a;
  v[1] = (__bf16)b;
  return __builtin_bit_cast(uint32_t, v);
}

__device__ __forceinline__ f32x4 mfma_bf16(u16x8 a, u16x8 b, f32x4 c) {
  return __builtin_amdgcn_mfma_f32_16x16x32_bf16(
      __builtin_bit_cast(bf16x8, a), __builtin_bit_cast(bf16x8, b), c, 0, 0, 0);
}

__device__ __forceinline__ void gload16(const u16* g, u16* l) {
  __builtin_amdgcn_global_load_lds((gas_vp)g, (las_vp)l, 16, 0, 0);
}

// ---------------- prep kernels ----------------

__global__ __launch_bounds__(256) void cast_x_kernel(const float* __restrict__ in,
                                                     u16* __restrict__ out, int n4) {
  int i = blockIdx.x * 256 + threadIdx.x;
  if (i < n4) {
    float4 v = ((const float4*)in)[i];
    ((uint2*)out)[i] = make_uint2(pack2bf(v.x, v.y), pack2bf(v.z, v.w));
  }
}

__global__ __launch_bounds__(256) void transpose_cast_kernel(
    const float* __restrict__ w0, const float* __restrict__ w1,
    const float* __restrict__ w2, const float* __restrict__ w3,
    u16* __restrict__ outQKV, u16* __restrict__ outO) {
  __shared__ float tile[32][33];
  const int m = blockIdx.z;
  const float* w = (m == 0) ? w0 : (m == 1) ? w1 : (m == 2) ? w2 : w3;
  const float scale = (m == 0) ? QSCALE : 1.0f;
  u16* out = (m < 3) ? (outQKV + (size_t)m * CDIM * CDIM) : outO;
  const int n0 = blockIdx.x * 32;
  const int k0 = blockIdx.y * 32;
  const int tx = threadIdx.x, ty = threadIdx.y;  // block (32, 8)
#pragma unroll
  for (int i = 0; i < 4; ++i)
    tile[ty + i * 8][tx] = w[(size_t)(k0 + ty + i * 8) * CDIM + n0 + tx];
  __syncthreads();
#pragma unroll
  for (int i = 0; i < 4; ++i)
    out[(size_t)(n0 + ty + i * 8) * CDIM + k0 + tx] = f2bf(tile[tx][ty + i * 8] * scale);
}

__global__ __launch_bounds__(256) void bias_concat_kernel(const float* __restrict__ bq,
                                                          const float* __restrict__ bk,
                                                          const float* __restrict__ bv,
                                                          float* __restrict__ out) {
  int i = blockIdx.x * 256 + threadIdx.x;
  if (i < 3 * CDIM) {
    float v = (i < CDIM) ? bq[i] * QSCALE
            : (i < 2 * CDIM) ? bk[i - CDIM] : bv[i - 2 * CDIM];
    out[i] = v;
  }
}

// V part of QKV [B*T][3C] -> Vt [B][H][D][T]
__global__ __launch_bounds__(256) void vtrans_kernel(const u16* __restrict__ QKV,
                                                     u16* __restrict__ Vt) {
  __shared__ u16 tile[32][33];
  const int bh = blockIdx.z;
  const int b = bh >> 4, h = bh & 15;
  const int t0 = blockIdx.x * 32, d0 = blockIdx.y * 32;
  const int tx = threadIdx.x, ty = threadIdx.y;  // block (32, 8)
#pragma unroll
  for (int i = 0; i < 4; ++i)
    tile[ty + i * 8][tx] =
        QKV[(size_t)(b * TSEQ + t0 + ty + i * 8) * (3 * CDIM) + 2 * CDIM + h * DHEAD + d0 + tx];
  __syncthreads();
#pragma unroll
  for (int i = 0; i < 4; ++i)
    Vt[(size_t)((b * NHEAD + h) * DHEAD + d0 + ty + i * 8) * TSEQ + t0 + tx] =
        tile[tx][ty + i * 8];
}

// ---------------- GEMM: C[M][N] = A[M][K] @ Bt[N][K]^T + bias ----------------
// 128x128 tile, BK=64 (half the barrier/drain events of BK=32), 4 waves,
// global_load_lds with PRE-SWIZZLED global source (linear LDS dest) + XOR-
// swizzled ds_read (rule #21 both-sides pattern); 1D grid + XCD swizzle.

template <typename OutT>
__global__ __launch_bounds__(256) void gemm_bt_kernel(
    const u16* __restrict__ A, const u16* __restrict__ Bt,
    const float* __restrict__ bias, OutT* __restrict__ C,
    int M, int N, int K, int mblocks) {
  __shared__ u16 As[128 * 64];  // 16KB, rows 128B
  __shared__ u16 Bs[128 * 64];
  const int nwg = gridDim.x;
  const int lid = blockIdx.x;
  const int swz = (lid & 7) * (nwg >> 3) + (lid >> 3);
  const int m0 = (swz % mblocks) * 128;
  const int n0 = (swz / mblocks) * 128;

  const int t = threadIdx.x;
  const int lane = t & 63;
  const int w = t >> 6;
  const int wr = w >> 1, wc = w & 1;
  const int l15 = lane & 15;
  const int lg = lane >> 4;
  const int xorv = (l15 & 7) << 4;

  // staging: chunk c = w*4+ci covers rows c*8..c*8+7; lane covers row c*8+(lane>>3)
  // source col is inverse-swizzled so linear gload_lds dest yields swizzled layout
  const int srow8 = lane >> 3;                                   // 0..7
  const int scol_swz = ((((lane & 7) << 4) ^ (srow8 << 4)) >> 1);  // u16 col

  f32x4 acc[4][4];
#pragma unroll
  for (int i = 0; i < 4; ++i)
#pragma unroll
    for (int j = 0; j < 4; ++j) acc[i][j] = f32x4{0.f, 0.f, 0.f, 0.f};

  for (int k0 = 0; k0 < K; k0 += 64) {
    __syncthreads();
#pragma unroll
    for (int ci = 0; ci < 4; ++ci) {
      const int c = w * 4 + ci;          // wave-uniform chunk 0..15
      const int grow = c * 8 + srow8;
      gload16(&A[(size_t)(m0 + grow) * K + k0 + scol_swz], &As[c * 512]);
      gload16(&Bt[(size_t)(n0 + grow) * K + k0 + scol_swz], &Bs[c * 512]);
    }
    __syncthreads();
#pragma unroll
    for (int kk = 0; kk < 2; ++kk) {
      u16x8 af[4], bf[4];
#pragma unroll
      for (int i = 0; i < 4; ++i)
        af[i] = *(const u16x8*)((char*)As + (wr * 64 + i * 16 + l15) * 128 +
                                ((kk * 64 + lg * 16) ^ xorv));
#pragma unroll
      for (int j = 0; j < 4; ++j)
        bf[j] = *(const u16x8*)((char*)Bs + (wc * 64 + j * 16 + l15) * 128 +
                                ((kk * 64 + lg * 16) ^ xorv));
#pragma unroll
      for (int i = 0; i < 4; ++i)
#pragma unroll
        for (int j = 0; j < 4; ++j) acc[i][j] = mfma_bf16(af[i], bf[j], acc[i][j]);
    }
  }

#pragma unroll
  for (int j = 0; j < 4; ++j) {
    int col = n0 + wc * 64 + j * 16 + l15;
    float bv = bias[col];
#pragma unroll
    for (int i = 0; i < 4; ++i) {
#pragma unroll
      for (int r = 0; r < 4; ++r) {
        int row = m0 + wr * 64 + i * 16 + lg * 4 + r;
        float val = acc[i][j][r] + bv;
        if constexpr (std::is_same<OutT, float>::value)
          C[(size_t)row * N + col] = val;
        else
          C[(size_t)row * N + col] = f2bf(val);
      }
    }
  }
}

// ---------------- causal flash attention (8-wave, dbuf, 1 barrier/tile) -----
// R7 compute structure (8 waves x 16 q-rows, XOR-swizzled LDS, swapped QK^T,
// exp2 softmax, vote-gated defer-max) with DOUBLE-BUFFERED K/V: per k-tile
// {write regs(kb+1)->buf^1 || issue loads(kb+2)->regs || compute buf} then ONE
// __syncthreads. bh->XCD pinning + LPT.

__global__ __launch_bounds__(512) void attn_kernel(const u16* __restrict__ QKV,
                                                   const u16* __restrict__ Vt,
                                                   u16* __restrict__ O) {
  __shared__ u16 Ks[2][64 * 64];    // 2 x 8KB
  __shared__ u16 Vs[2][64 * 64];    // 2 x 8KB, V^T tile [d=64][k=64]
  __shared__ u16 Ps[8 * 16 * 64];   // per-wave 16-row P / O staging (16KB)

  const int t = threadIdx.x;
  const int lane = t & 63;
  const int w = t >> 6;             // 0..7
  const int l15 = lane & 15, lg = lane >> 4;
  const int xorv = (l15 & 7) << 4;

  // bh->XCD pinning + LPT
  const int lid = blockIdx.x;       // 0..511
  const int xcd = lid & 7;
  const int m = lid >> 3;           // 0..63
  const int bh = (m & 3) * 8 + xcd; // 0..31
  const int qt = 15 - (m >> 2);     // 0..15, heavy first
  const int b = bh >> 4, h = bh & 15;
  const int q0 = qt * 128;
  const int qrow = q0 + w * 16;     // wave's 16 q-rows
  const int nkt = (qt + 1) * 2;     // k-tiles of 64 (block-uniform, >= 2)

  const size_t RS = 3 * CDIM;
  const u16* Qp  = QKV + (size_t)(b * TSEQ) * RS + h * DHEAD;
  const u16* Kp  = Qp + CDIM;
  const u16* Vgp = Vt + (size_t)(b * NHEAD + h) * DHEAD * TSEQ;
  char* PwB = (char*)&Ps[w * 16 * 64];

  // Q fragment (B-operand): row q = qrow+l15, k elems lg*8..
  u16x8 qf[2];
#pragma unroll
  for (int c = 0; c < 2; ++c)
    qf[c] = *(const u16x8*)(&Qp[(size_t)(qrow + l15) * RS + c * 32 + lg * 8]);

  f32x4 acc[4];
#pragma unroll
  for (int g = 0; g < 4; ++g) acc[g] = f32x4{0.f, 0.f, 0.f, 0.f};
  float m_run = -3e38f, l_run = 0.f;

  // staging: 512 threads, 1 chunk each for K and V; swizzled LDS byte addr
  const int sr = t >> 3;            // 0..63
  const int sch = t & 7;            // 16B chunk 0..7
  const int swA = sr * 128 + ((sch * 16) ^ ((sr & 7) << 4));

  // prologue: tile0 -> regs -> buf0; tile1 -> regs; one barrier
  u16x8 kreg = *(const u16x8*)(&Kp[(size_t)sr * RS + sch * 8]);
  u16x8 vreg = *(const u16x8*)(&Vgp[(size_t)sr * TSEQ + sch * 8]);
  *(u16x8*)((char*)Ks[0] + swA) = kreg;
  *(u16x8*)((char*)Vs[0] + swA) = vreg;
  kreg = *(const u16x8*)(&Kp[(size_t)(64 + sr) * RS + sch * 8]);
  vreg = *(const u16x8*)(&Vgp[(size_t)sr * TSEQ + 64 + sch * 8]);
  __syncthreads();

  for (int kb = 0; kb < nkt; ++kb) {
    const int p = kb & 1;
    char* KsB = (char*)Ks[p];
    char* VsB = (char*)Vs[p];

    // write next tile (kb+1, held in regs) into the other buffer
    if (kb + 1 < nkt) {
      *(u16x8*)((char*)Ks[p ^ 1] + swA) = kreg;
      *(u16x8*)((char*)Vs[p ^ 1] + swA) = vreg;
    }
    // issue loads for kb+2; latency hides under compute below
    if (kb + 2 < nkt) {
      kreg = *(const u16x8*)(&Kp[(size_t)((kb + 2) * 64 + sr) * RS + sch * 8]);
      vreg = *(const u16x8*)(&Vgp[(size_t)sr * TSEQ + (kb + 2) * 64 + sch * 8]);
    }

    if (kb * 64 <= qrow + 15) {  // skip fully-masked tiles (stage duty only)
      // S^T[k][q]: rows k = f*16+lg*4+r, col q = l15 (pre-scaled by QSCALE)
      f32x4 sfr[4];
      __builtin_amdgcn_s_setprio(1);
#pragma unroll
      for (int f = 0; f < 4; ++f) {
        const char* rowp = KsB + (f * 16 + l15) * 128;
        u16x8 k0 = *(const u16x8*)(rowp + ((lg * 16) ^ xorv));
        u16x8 k1 = *(const u16x8*)(rowp + ((64 + lg * 16) ^ xorv));
        f32x4 s = mfma_bf16(k0, qf[0], f32x4{0.f, 0.f, 0.f, 0.f});
        sfr[f] = mfma_bf16(k1, qf[1], s);
      }
      __builtin_amdgcn_s_setprio(0);

      if (kb * 64 + 63 > qrow) {  // causal mask (wave-uniform predicate)
        const int q_abs = qrow + l15;
#pragma unroll
        for (int f = 0; f < 4; ++f) {
          const int kbase = kb * 64 + f * 16 + lg * 4;
#pragma unroll
          for (int r = 0; r < 4; ++r)
            if (kbase + r > q_abs) sfr[f][r] = -1e9f;
        }
      }

      // row-max: in-lane over 16; wave vote gates rescale (T13, THR=8)
      float mx = sfr[0][0];
#pragma unroll
      for (int f = 0; f < 4; ++f)
#pragma unroll
        for (int r = 0; r < 4; ++r) mx = fmaxf(mx, sfr[f][r]);

      if (__any(mx > m_run + 8.f)) {
        float gm = mx;
        gm = fmaxf(gm, __shfl_xor(gm, 16));
        gm = fmaxf(gm, __shfl_xor(gm, 32));
        float mnew = fmaxf(m_run, gm);
        float fac = exp2f(m_run - mnew);
        m_run = mnew;
        l_run *= fac;
#pragma unroll
        for (int g = 0; g < 4; ++g) acc[g] *= fac;
      }

      // P = exp2(S - m); per-lane partial l; packed u32 -> swizzled Pw
      {
        char* pb = PwB + l15 * 128;
        float ls = 0.f;
#pragma unroll
        for (int f = 0; f < 4; ++f) {
          float p0 = exp2f(sfr[f][0] - m_run);
          float p1 = exp2f(sfr[f][1] - m_run);
          float p2 = exp2f(sfr[f][2] - m_run);
          float p3 = exp2f(sfr[f][3] - m_run);
          ls += (p0 + p1) + (p2 + p3);
          const int boff = (f * 32 + lg * 8) ^ xorv;  // stays 8B-aligned
          *(uint32_t*)(pb + boff) = pack2bf(p0, p1);
          *(uint32_t*)(pb + boff + 4) = pack2bf(p2, p3);
        }
        l_run += ls;
      }

      // O^T += mfma(V^T, P)
      __builtin_amdgcn_s_setprio(1);
#pragma unroll
      for (int c = 0; c < 2; ++c) {
        const int coff = (c * 64 + lg * 16) ^ xorv;
        u16x8 pf = *(const u16x8*)(PwB + l15 * 128 + coff);
#pragma unroll
        for (int g = 0; g < 4; ++g) {
          u16x8 vf = *(const u16x8*)(VsB + (g * 16 + l15) * 128 + coff);
          acc[g] = mfma_bf16(vf, pf, acc[g]);
        }
      }
      __builtin_amdgcn_s_setprio(0);
    }

    __syncthreads();  // single barrier per k-tile
  }

  // epilogue: reduce l across lane-groups, normalize, un-transpose via Pw
  float lt = l_run;
  lt += __shfl_xor(lt, 16);
  lt += __shfl_xor(lt, 32);
  float inv = 1.f / lt;
  {
    char* pb = PwB + l15 * 128;
#pragma unroll
    for (int g = 0; g < 4; ++g) {
      const int boff = (g * 32 + lg * 8) ^ xorv;
      *(uint32_t*)(pb + boff) = pack2bf(acc[g][0] * inv, acc[g][1] * inv);
      *(uint32_t*)(pb + boff + 4) = pack2bf(acc[g][2] * inv, acc[g][3] * inv);
    }
  }
#pragma unroll
  for (int i = 0; i < 2; ++i) {
    const int rl = i * 8 + (lane >> 3);  // 0..15
    const int ch = lane & 7;
    u16x8 vv = *(const u16x8*)(PwB + rl * 128 + ((ch * 16) ^ ((rl & 7) << 4)));
    *(u16x8*)(&O[(size_t)(b * TSEQ + qrow + rl) * CDIM + h * DHEAD + ch * 8]) = vv;
  }
}

// ---------------- launch ----------------

extern "C" void kernel_launch(void* const* d_in, const int* in_sizes, int n_in,
                              void* d_out, int out_size, void* d_ws, size_t ws_size,
                              hipStream_t stream) {
  const float* x  = (const float*)d_in[0];
  const float* wq = (const float*)d_in[1];
  const float* bq = (const float*)d_in[2];
  const float* wk = (const float*)d_in[3];
  const float* bk = (const float*)d_in[4];
  const float* wv = (const float*)d_in[5];
  const float* bv = (const float*)d_in[6];
  const float* wo = (const float*)d_in[7];
  const float* bo = (const float*)d_in[8];
  float* out = (float*)d_out;

  char* ws = (char*)d_ws;
  u16*  xb      = (u16*)(ws);                 // 8MB; dead after QKV GEMM
  u16*  Vtg     = (u16*)(ws);                 // aliases xb (written after)
  u16*  wqkvT   = (u16*)(ws + (8ll << 20));
  u16*  woT     = (u16*)(ws + (14ll << 20));
  u16*  QKV     = (u16*)(ws + (16ll << 20));
  u16*  Obuf    = (u16*)(ws + (40ll << 20));
  float* biasqkv = (float*)(ws + (48ll << 20));

  cast_x_kernel<<<(NROWS * CDIM / 4 + 255) / 256, 256, 0, stream>>>(x, xb, NROWS * CDIM / 4);
  {
    dim3 g(CDIM / 32, CDIM / 32, 4), blk(32, 8);
    transpose_cast_kernel<<<g, blk, 0, stream>>>(wq, wk, wv, wo, wqkvT, woT);
  }
  bias_concat_kernel<<<12, 256, 0, stream>>>(bq, bk, bv, biasqkv);
  gemm_bt_kernel<u16><<<(NROWS / 128) * ((3 * CDIM) / 128), 256, 0, stream>>>(
      xb, wqkvT, biasqkv, QKV, NROWS, 3 * CDIM, CDIM, NROWS / 128);
  {
    dim3 g(TSEQ / 32, DHEAD / 32, BATCH * NHEAD), blk(32, 8);
    vtrans_kernel<<<g, blk, 0, stream>>>(QKV, Vtg);
  }
  attn_kernel<<<512, 512, 0, stream>>>(QKV, Vtg, Obuf);
  gemm_bt_kernel<float><<<(NROWS / 128) * (CDIM / 128), 256, 0, stream>>>(
      Obuf, woT, bo, out, NROWS, CDIM, CDIM, NROWS / 128);
}

// Round 10
// 133.711 us; speedup vs baseline: 1.0494x; 1.0170x over previous
//
#include <hip/hip_runtime.h>
#include <cstdint>
#include <type_traits>

// GPT MHA forward. B=2, T=2048, C=1024, H=16, d=64.
// cast x->bf16 | transpose weights (wq pre-scaled 0.125*log2e) | bias concat
// | QKV GEMM (128x128, BK=32, gload_lds — proven R7 structure) | V-transpose
// | causal flash attn (8 waves x 16 q-rows, double-buffered K/V, ONE barrier
//   per k-tile, XOR-swizzled LDS, swapped QK^T, exp2 softmax, defer-max,
//   bh->XCD pinning, masked-tile skip) | out-proj GEMM.

#define TSEQ  2048
#define BATCH 2
#define CDIM  1024
#define NHEAD 16
#define DHEAD 64
#define NROWS (BATCH * TSEQ)  // 4096

// 0.125 (1/sqrt(d)) * log2(e): folded into wq/bq so softmax uses exp2
#define QSCALE 0.1803368801111244f

typedef unsigned short u16;
typedef u16   u16x8  __attribute__((ext_vector_type(8)));
typedef __bf16 bf16x8 __attribute__((ext_vector_type(8)));
typedef __bf16 bf16x2 __attribute__((ext_vector_type(2)));
typedef float f32x4  __attribute__((ext_vector_type(4)));

typedef const __attribute__((address_space(1))) void* gas_vp;
typedef __attribute__((address_space(3))) void* las_vp;

__device__ __forceinline__ u16 f2bf(float f) {
  return __builtin_bit_cast(u16, (__bf16)f);
}

__device__ __forceinline__ uint32_t pack2bf(float a, float b) {
  bf16x2 v;
  v[0] = (__bf16)a;
  v[1] = (__bf16)b;
  return __builtin_bit_cast(uint32_t, v);
}

__device__ __forceinline__ f32x4 mfma_bf16(u16x8 a, u16x8 b, f32x4 c) {
  return __builtin_amdgcn_mfma_f32_16x16x32_bf16(
      __builtin_bit_cast(bf16x8, a), __builtin_bit_cast(bf16x8, b), c, 0, 0, 0);
}

__device__ __forceinline__ void gload16(const u16* g, u16* l) {
  __builtin_amdgcn_global_load_lds((gas_vp)g, (las_vp)l, 16, 0, 0);
}

// ---------------- prep kernels ----------------

__global__ __launch_bounds__(256) void cast_x_kernel(const float* __restrict__ in,
                                                     u16* __restrict__ out, int n4) {
  int i = blockIdx.x * 256 + threadIdx.x;
  if (i < n4) {
    float4 v = ((const float4*)in)[i];
    ((uint2*)out)[i] = make_uint2(pack2bf(v.x, v.y), pack2bf(v.z, v.w));
  }
}

__global__ __launch_bounds__(256) void transpose_cast_kernel(
    const float* __restrict__ w0, const float* __restrict__ w1,
    const float* __restrict__ w2, const float* __restrict__ w3,
    u16* __restrict__ outQKV, u16* __restrict__ outO) {
  __shared__ float tile[32][33];
  const int m = blockIdx.z;
  const float* w = (m == 0) ? w0 : (m == 1) ? w1 : (m == 2) ? w2 : w3;
  const float scale = (m == 0) ? QSCALE : 1.0f;
  u16* out = (m < 3) ? (outQKV + (size_t)m * CDIM * CDIM) : outO;
  const int n0 = blockIdx.x * 32;
  const int k0 = blockIdx.y * 32;
  const int tx = threadIdx.x, ty = threadIdx.y;  // block (32, 8)
#pragma unroll
  for (int i = 0; i < 4; ++i)
    tile[ty + i * 8][tx] = w[(size_t)(k0 + ty + i * 8) * CDIM + n0 + tx];
  __syncthreads();
#pragma unroll
  for (int i = 0; i < 4; ++i)
    out[(size_t)(n0 + ty + i * 8) * CDIM + k0 + tx] = f2bf(tile[tx][ty + i * 8] * scale);
}

__global__ __launch_bounds__(256) void bias_concat_kernel(const float* __restrict__ bq,
                                                          const float* __restrict__ bk,
                                                          const float* __restrict__ bv,
                                                          float* __restrict__ out) {
  int i = blockIdx.x * 256 + threadIdx.x;
  if (i < 3 * CDIM) {
    float v = (i < CDIM) ? bq[i] * QSCALE
            : (i < 2 * CDIM) ? bk[i - CDIM] : bv[i - 2 * CDIM];
    out[i] = v;
  }
}

// V part of QKV [B*T][3C] -> Vt [B][H][D][T]
__global__ __launch_bounds__(256) void vtrans_kernel(const u16* __restrict__ QKV,
                                                     u16* __restrict__ Vt) {
  __shared__ u16 tile[32][33];
  const int bh = blockIdx.z;
  const int b = bh >> 4, h = bh & 15;
  const int t0 = blockIdx.x * 32, d0 = blockIdx.y * 32;
  const int tx = threadIdx.x, ty = threadIdx.y;  // block (32, 8)
#pragma unroll
  for (int i = 0; i < 4; ++i)
    tile[ty + i * 8][tx] =
        QKV[(size_t)(b * TSEQ + t0 + ty + i * 8) * (3 * CDIM) + 2 * CDIM + h * DHEAD + d0 + tx];
  __syncthreads();
#pragma unroll
  for (int i = 0; i < 4; ++i)
    Vt[(size_t)((b * NHEAD + h) * DHEAD + d0 + ty + i * 8) * TSEQ + t0 + tx] =
        tile[tx][ty + i * 8];
}

// ---------------- GEMM: C[M][N] = A[M][K] @ Bt[N][K]^T + bias ----------------
// 128x128 tile, BK=32, 4 waves, global_load_lds staging; 1D grid + XCD swizzle.
// (proven R7 structure; BK=64 variant measured -8us in R9, reverted)

template <typename OutT>
__global__ __launch_bounds__(256) void gemm_bt_kernel(
    const u16* __restrict__ A, const u16* __restrict__ Bt,
    const float* __restrict__ bias, OutT* __restrict__ C,
    int M, int N, int K, int mblocks) {
  __shared__ u16 As[128 * 32];
  __shared__ u16 Bs[128 * 32];
  const int nwg = gridDim.x;
  const int lid = blockIdx.x;
  const int swz = (lid & 7) * (nwg >> 3) + (lid >> 3);
  const int m0 = (swz % mblocks) * 128;
  const int n0 = (swz / mblocks) * 128;

  const int t = threadIdx.x;
  const int lane = t & 63;
  const int w = t >> 6;
  const int wr = w >> 1, wc = w & 1;
  const int l15 = lane & 15;
  const int lg = lane >> 4;
  const int srow = lane >> 2;
  const int scol = (lane & 3) * 8;

  f32x4 acc[4][4];
#pragma unroll
  for (int i = 0; i < 4; ++i)
#pragma unroll
    for (int j = 0; j < 4; ++j) acc[i][j] = f32x4{0.f, 0.f, 0.f, 0.f};

  for (int k0 = 0; k0 < K; k0 += 32) {
    __syncthreads();
#pragma unroll
    for (int ci = 0; ci < 2; ++ci) {
      const int chunk = w * 2 + ci;
      const int grow = chunk * 16 + srow;
      gload16(&A[(size_t)(m0 + grow) * K + k0 + scol], &As[chunk * 512]);
      gload16(&Bt[(size_t)(n0 + grow) * K + k0 + scol], &Bs[chunk * 512]);
    }
    __syncthreads();
    u16x8 af[4], bf[4];
#pragma unroll
    for (int i = 0; i < 4; ++i)
      af[i] = *(const u16x8*)(&As[(wr * 64 + i * 16 + l15) * 32 + lg * 8]);
#pragma unroll
    for (int j = 0; j < 4; ++j)
      bf[j] = *(const u16x8*)(&Bs[(wc * 64 + j * 16 + l15) * 32 + lg * 8]);
#pragma unroll
    for (int i = 0; i < 4; ++i)
#pragma unroll
      for (int j = 0; j < 4; ++j) acc[i][j] = mfma_bf16(af[i], bf[j], acc[i][j]);
  }

#pragma unroll
  for (int j = 0; j < 4; ++j) {
    int col = n0 + wc * 64 + j * 16 + l15;
    float bv = bias[col];
#pragma unroll
    for (int i = 0; i < 4; ++i) {
#pragma unroll
      for (int r = 0; r < 4; ++r) {
        int row = m0 + wr * 64 + i * 16 + lg * 4 + r;
        float val = acc[i][j][r] + bv;
        if constexpr (std::is_same<OutT, float>::value)
          C[(size_t)row * N + col] = val;
        else
          C[(size_t)row * N + col] = f2bf(val);
      }
    }
  }
}

// ---------------- causal flash attention (8-wave, dbuf, 1 barrier/tile) -----
// 8 waves x 16 q-rows, XOR-swizzled LDS, swapped QK^T, exp2 softmax,
// vote-gated defer-max; DOUBLE-BUFFERED K/V: per k-tile {write regs(kb+1)->
// buf^1 || issue loads(kb+2)->regs || compute buf} then ONE __syncthreads.
// bh->XCD pinning + LPT. P-writes packed as ds_write_b64.

__global__ __launch_bounds__(512) void attn_kernel(const u16* __restrict__ QKV,
                                                   const u16* __restrict__ Vt,
                                                   u16* __restrict__ O) {
  __shared__ u16 Ks[2][64 * 64];    // 2 x 8KB
  __shared__ u16 Vs[2][64 * 64];    // 2 x 8KB, V^T tile [d=64][k=64]
  __shared__ u16 Ps[8 * 16 * 64];   // per-wave 16-row P / O staging (16KB)

  const int t = threadIdx.x;
  const int lane = t & 63;
  const int w = t >> 6;             // 0..7
  const int l15 = lane & 15, lg = lane >> 4;
  const int xorv = (l15 & 7) << 4;

  // bh->XCD pinning + LPT
  const int lid = blockIdx.x;       // 0..511
  const int xcd = lid & 7;
  const int m = lid >> 3;           // 0..63
  const int bh = (m & 3) * 8 + xcd; // 0..31
  const int qt = 15 - (m >> 2);     // 0..15, heavy first
  const int b = bh >> 4, h = bh & 15;
  const int q0 = qt * 128;
  const int qrow = q0 + w * 16;     // wave's 16 q-rows
  const int nkt = (qt + 1) * 2;     // k-tiles of 64 (block-uniform, >= 2)

  const size_t RS = 3 * CDIM;
  const u16* Qp  = QKV + (size_t)(b * TSEQ) * RS + h * DHEAD;
  const u16* Kp  = Qp + CDIM;
  const u16* Vgp = Vt + (size_t)(b * NHEAD + h) * DHEAD * TSEQ;
  char* PwB = (char*)&Ps[w * 16 * 64];

  // Q fragment (B-operand): row q = qrow+l15, k elems lg*8..
  u16x8 qf[2];
#pragma unroll
  for (int c = 0; c < 2; ++c)
    qf[c] = *(const u16x8*)(&Qp[(size_t)(qrow + l15) * RS + c * 32 + lg * 8]);

  f32x4 acc[4];
#pragma unroll
  for (int g = 0; g < 4; ++g) acc[g] = f32x4{0.f, 0.f, 0.f, 0.f};
  float m_run = -3e38f, l_run = 0.f;

  // staging: 512 threads, 1 chunk each for K and V; swizzled LDS byte addr
  const int sr = t >> 3;            // 0..63
  const int sch = t & 7;            // 16B chunk 0..7
  const int swA = sr * 128 + ((sch * 16) ^ ((sr & 7) << 4));

  // prologue: tile0 -> regs -> buf0; tile1 -> regs; one barrier
  u16x8 kreg = *(const u16x8*)(&Kp[(size_t)sr * RS + sch * 8]);
  u16x8 vreg = *(const u16x8*)(&Vgp[(size_t)sr * TSEQ + sch * 8]);
  *(u16x8*)((char*)Ks[0] + swA) = kreg;
  *(u16x8*)((char*)Vs[0] + swA) = vreg;
  kreg = *(const u16x8*)(&Kp[(size_t)(64 + sr) * RS + sch * 8]);
  vreg = *(const u16x8*)(&Vgp[(size_t)sr * TSEQ + 64 + sch * 8]);
  __syncthreads();

  for (int kb = 0; kb < nkt; ++kb) {
    const int p = kb & 1;
    char* KsB = (char*)Ks[p];
    char* VsB = (char*)Vs[p];

    // write next tile (kb+1, held in regs) into the other buffer
    if (kb + 1 < nkt) {
      *(u16x8*)((char*)Ks[p ^ 1] + swA) = kreg;
      *(u16x8*)((char*)Vs[p ^ 1] + swA) = vreg;
    }
    // issue loads for kb+2; latency hides under compute below
    if (kb + 2 < nkt) {
      kreg = *(const u16x8*)(&Kp[(size_t)((kb + 2) * 64 + sr) * RS + sch * 8]);
      vreg = *(const u16x8*)(&Vgp[(size_t)sr * TSEQ + (kb + 2) * 64 + sch * 8]);
    }

    if (kb * 64 <= qrow + 15) {  // skip fully-masked tiles (stage duty only)
      // S^T[k][q]: rows k = f*16+lg*4+r, col q = l15 (pre-scaled by QSCALE)
      f32x4 sfr[4];
      __builtin_amdgcn_s_setprio(1);
#pragma unroll
      for (int f = 0; f < 4; ++f) {
        const char* rowp = KsB + (f * 16 + l15) * 128;
        u16x8 k0 = *(const u16x8*)(rowp + ((lg * 16) ^ xorv));
        u16x8 k1 = *(const u16x8*)(rowp + ((64 + lg * 16) ^ xorv));
        f32x4 s = mfma_bf16(k0, qf[0], f32x4{0.f, 0.f, 0.f, 0.f});
        sfr[f] = mfma_bf16(k1, qf[1], s);
      }
      __builtin_amdgcn_s_setprio(0);

      if (kb * 64 + 63 > qrow) {  // causal mask (wave-uniform predicate)
        const int q_abs = qrow + l15;
#pragma unroll
        for (int f = 0; f < 4; ++f) {
          const int kbase = kb * 64 + f * 16 + lg * 4;
#pragma unroll
          for (int r = 0; r < 4; ++r)
            if (kbase + r > q_abs) sfr[f][r] = -1e9f;
        }
      }

      // row-max: in-lane over 16; wave vote gates rescale (T13, THR=8)
      float mx = sfr[0][0];
#pragma unroll
      for (int f = 0; f < 4; ++f)
#pragma unroll
        for (int r = 0; r < 4; ++r) mx = fmaxf(mx, sfr[f][r]);

      if (__any(mx > m_run + 8.f)) {
        float gm = mx;
        gm = fmaxf(gm, __shfl_xor(gm, 16));
        gm = fmaxf(gm, __shfl_xor(gm, 32));
        float mnew = fmaxf(m_run, gm);
        float fac = exp2f(m_run - mnew);
        m_run = mnew;
        l_run *= fac;
#pragma unroll
        for (int g = 0; g < 4; ++g) acc[g] *= fac;
      }

      // P = exp2(S - m); per-lane partial l; packed b64 -> swizzled Pw
      {
        char* pb = PwB + l15 * 128;
        float ls = 0.f;
#pragma unroll
        for (int f = 0; f < 4; ++f) {
          float p0 = exp2f(sfr[f][0] - m_run);
          float p1 = exp2f(sfr[f][1] - m_run);
          float p2 = exp2f(sfr[f][2] - m_run);
          float p3 = exp2f(sfr[f][3] - m_run);
          ls += (p0 + p1) + (p2 + p3);
          const int boff = (f * 32 + lg * 8) ^ xorv;  // 8B-aligned
          *(uint2*)(pb + boff) = make_uint2(pack2bf(p0, p1), pack2bf(p2, p3));
        }
        l_run += ls;
      }

      // O^T += mfma(V^T, P)
      __builtin_amdgcn_s_setprio(1);
#pragma unroll
      for (int c = 0; c < 2; ++c) {
        const int coff = (c * 64 + lg * 16) ^ xorv;
        u16x8 pf = *(const u16x8*)(PwB + l15 * 128 + coff);
#pragma unroll
        for (int g = 0; g < 4; ++g) {
          u16x8 vf = *(const u16x8*)(VsB + (g * 16 + l15) * 128 + coff);
          acc[g] = mfma_bf16(vf, pf, acc[g]);
        }
      }
      __builtin_amdgcn_s_setprio(0);
    }

    __syncthreads();  // single barrier per k-tile
  }

  // epilogue: reduce l across lane-groups, normalize, un-transpose via Pw
  float lt = l_run;
  lt += __shfl_xor(lt, 16);
  lt += __shfl_xor(lt, 32);
  float inv = 1.f / lt;
  {
    char* pb = PwB + l15 * 128;
#pragma unroll
    for (int g = 0; g < 4; ++g) {
      const int boff = (g * 32 + lg * 8) ^ xorv;
      *(uint2*)(pb + boff) = make_uint2(pack2bf(acc[g][0] * inv, acc[g][1] * inv),
                                        pack2bf(acc[g][2] * inv, acc[g][3] * inv));
    }
  }
#pragma unroll
  for (int i = 0; i < 2; ++i) {
    const int rl = i * 8 + (lane >> 3);  // 0..15
    const int ch = lane & 7;
    u16x8 vv = *(const u16x8*)(PwB + rl * 128 + ((ch * 16) ^ ((rl & 7) << 4)));
    *(u16x8*)(&O[(size_t)(b * TSEQ + qrow + rl) * CDIM + h * DHEAD + ch * 8]) = vv;
  }
}

// ---------------- launch ----------------

extern "C" void kernel_launch(void* const* d_in, const int* in_sizes, int n_in,
                              void* d_out, int out_size, void* d_ws, size_t ws_size,
                              hipStream_t stream) {
  const float* x  = (const float*)d_in[0];
  const float* wq = (const float*)d_in[1];
  const float* bq = (const float*)d_in[2];
  const float* wk = (const float*)d_in[3];
  const float* bk = (const float*)d_in[4];
  const float* wv = (const float*)d_in[5];
  const float* bv = (const float*)d_in[6];
  const float* wo = (const float*)d_in[7];
  const float* bo = (const float*)d_in[8];
  float* out = (float*)d_out;

  char* ws = (char*)d_ws;
  u16*  xb      = (u16*)(ws);                 // 8MB; dead after QKV GEMM
  u16*  Vtg     = (u16*)(ws);                 // aliases xb (written after)
  u16*  wqkvT   = (u16*)(ws + (8ll << 20));
  u16*  woT     = (u16*)(ws + (14ll << 20));
  u16*  QKV     = (u16*)(ws + (16ll << 20));
  u16*  Obuf    = (u16*)(ws + (40ll << 20));
  float* biasqkv = (float*)(ws + (48ll << 20));

  cast_x_kernel<<<(NROWS * CDIM / 4 + 255) / 256, 256, 0, stream>>>(x, xb, NROWS * CDIM / 4);
  {
    dim3 g(CDIM / 32, CDIM / 32, 4), blk(32, 8);
    transpose_cast_kernel<<<g, blk, 0, stream>>>(wq, wk, wv, wo, wqkvT, woT);
  }
  bias_concat_kernel<<<12, 256, 0, stream>>>(bq, bk, bv, biasqkv);
  gemm_bt_kernel<u16><<<(NROWS / 128) * ((3 * CDIM) / 128), 256, 0, stream>>>(
      xb, wqkvT, biasqkv, QKV, NROWS, 3 * CDIM, CDIM, NROWS / 128);
  {
    dim3 g(TSEQ / 32, DHEAD / 32, BATCH * NHEAD), blk(32, 8);
    vtrans_kernel<<<g, blk, 0, stream>>>(QKV, Vtg);
  }
  attn_kernel<<<512, 512, 0, stream>>>(QKV, Vtg, Obuf);
  gemm_bt_kernel<float><<<(NROWS / 128) * (CDIM / 128), 256, 0, stream>>>(
      Obuf, woT, bo, out, NROWS, CDIM, CDIM, NROWS / 128);
}

// Round 11
// 133.622 us; speedup vs baseline: 1.0501x; 1.0007x over previous
//
#include <hip/hip_runtime.h>
#include <cstdint>
#include <type_traits>

// GPT MHA forward. B=2, T=2048, C=1024, H=16, d=64.
// cast x->bf16 | transpose weights (wq pre-scaled 0.125*log2e) | bias concat
// | QKV GEMM (128x128, BK=32, gload_lds — proven structure) | V-transpose
// | causal flash attn (4 waves x 16 q-rows, 64 q/block, grid 1024,
//   double-buffered K/V, 1 barrier/k-tile, XOR-swizzled LDS, swapped QK^T,
//   exp2 softmax, defer-max, bh->XCD pinning + LPT) | out-proj GEMM.

#define TSEQ  2048
#define BATCH 2
#define CDIM  1024
#define NHEAD 16
#define DHEAD 64
#define NROWS (BATCH * TSEQ)  // 4096

// 0.125 (1/sqrt(d)) * log2(e): folded into wq/bq so softmax uses exp2
#define QSCALE 0.1803368801111244f

typedef unsigned short u16;
typedef u16   u16x8  __attribute__((ext_vector_type(8)));
typedef __bf16 bf16x8 __attribute__((ext_vector_type(8)));
typedef __bf16 bf16x2 __attribute__((ext_vector_type(2)));
typedef float f32x4  __attribute__((ext_vector_type(4)));

typedef const __attribute__((address_space(1))) void* gas_vp;
typedef __attribute__((address_space(3))) void* las_vp;

__device__ __forceinline__ u16 f2bf(float f) {
  return __builtin_bit_cast(u16, (__bf16)f);
}

__device__ __forceinline__ uint32_t pack2bf(float a, float b) {
  bf16x2 v;
  v[0] = (__bf16)a;
  v[1] = (__bf16)b;
  return __builtin_bit_cast(uint32_t, v);
}

__device__ __forceinline__ f32x4 mfma_bf16(u16x8 a, u16x8 b, f32x4 c) {
  return __builtin_amdgcn_mfma_f32_16x16x32_bf16(
      __builtin_bit_cast(bf16x8, a), __builtin_bit_cast(bf16x8, b), c, 0, 0, 0);
}

__device__ __forceinline__ void gload16(const u16* g, u16* l) {
  __builtin_amdgcn_global_load_lds((gas_vp)g, (las_vp)l, 16, 0, 0);
}

// ---------------- prep kernels ----------------

__global__ __launch_bounds__(256) void cast_x_kernel(const float* __restrict__ in,
                                                     u16* __restrict__ out, int n4) {
  int i = blockIdx.x * 256 + threadIdx.x;
  if (i < n4) {
    float4 v = ((const float4*)in)[i];
    ((uint2*)out)[i] = make_uint2(pack2bf(v.x, v.y), pack2bf(v.z, v.w));
  }
}

__global__ __launch_bounds__(256) void transpose_cast_kernel(
    const float* __restrict__ w0, const float* __restrict__ w1,
    const float* __restrict__ w2, const float* __restrict__ w3,
    u16* __restrict__ outQKV, u16* __restrict__ outO) {
  __shared__ float tile[32][33];
  const int m = blockIdx.z;
  const float* w = (m == 0) ? w0 : (m == 1) ? w1 : (m == 2) ? w2 : w3;
  const float scale = (m == 0) ? QSCALE : 1.0f;
  u16* out = (m < 3) ? (outQKV + (size_t)m * CDIM * CDIM) : outO;
  const int n0 = blockIdx.x * 32;
  const int k0 = blockIdx.y * 32;
  const int tx = threadIdx.x, ty = threadIdx.y;  // block (32, 8)
#pragma unroll
  for (int i = 0; i < 4; ++i)
    tile[ty + i * 8][tx] = w[(size_t)(k0 + ty + i * 8) * CDIM + n0 + tx];
  __syncthreads();
#pragma unroll
  for (int i = 0; i < 4; ++i)
    out[(size_t)(n0 + ty + i * 8) * CDIM + k0 + tx] = f2bf(tile[tx][ty + i * 8] * scale);
}

__global__ __launch_bounds__(256) void bias_concat_kernel(const float* __restrict__ bq,
                                                          const float* __restrict__ bk,
                                                          const float* __restrict__ bv,
                                                          float* __restrict__ out) {
  int i = blockIdx.x * 256 + threadIdx.x;
  if (i < 3 * CDIM) {
    float v = (i < CDIM) ? bq[i] * QSCALE
            : (i < 2 * CDIM) ? bk[i - CDIM] : bv[i - 2 * CDIM];
    out[i] = v;
  }
}

// V part of QKV [B*T][3C] -> Vt [B][H][D][T]
__global__ __launch_bounds__(256) void vtrans_kernel(const u16* __restrict__ QKV,
                                                     u16* __restrict__ Vt) {
  __shared__ u16 tile[32][33];
  const int bh = blockIdx.z;
  const int b = bh >> 4, h = bh & 15;
  const int t0 = blockIdx.x * 32, d0 = blockIdx.y * 32;
  const int tx = threadIdx.x, ty = threadIdx.y;  // block (32, 8)
#pragma unroll
  for (int i = 0; i < 4; ++i)
    tile[ty + i * 8][tx] =
        QKV[(size_t)(b * TSEQ + t0 + ty + i * 8) * (3 * CDIM) + 2 * CDIM + h * DHEAD + d0 + tx];
  __syncthreads();
#pragma unroll
  for (int i = 0; i < 4; ++i)
    Vt[(size_t)((b * NHEAD + h) * DHEAD + d0 + ty + i * 8) * TSEQ + t0 + tx] =
        tile[tx][ty + i * 8];
}

// ---------------- GEMM: C[M][N] = A[M][K] @ Bt[N][K]^T + bias ----------------
// 128x128 tile, BK=32, 4 waves, global_load_lds staging; 1D grid + XCD swizzle.

template <typename OutT>
__global__ __launch_bounds__(256) void gemm_bt_kernel(
    const u16* __restrict__ A, const u16* __restrict__ Bt,
    const float* __restrict__ bias, OutT* __restrict__ C,
    int M, int N, int K, int mblocks) {
  __shared__ u16 As[128 * 32];
  __shared__ u16 Bs[128 * 32];
  const int nwg = gridDim.x;
  const int lid = blockIdx.x;
  const int swz = (lid & 7) * (nwg >> 3) + (lid >> 3);
  const int m0 = (swz % mblocks) * 128;
  const int n0 = (swz / mblocks) * 128;

  const int t = threadIdx.x;
  const int lane = t & 63;
  const int w = t >> 6;
  const int wr = w >> 1, wc = w & 1;
  const int l15 = lane & 15;
  const int lg = lane >> 4;
  const int srow = lane >> 2;
  const int scol = (lane & 3) * 8;

  f32x4 acc[4][4];
#pragma unroll
  for (int i = 0; i < 4; ++i)
#pragma unroll
    for (int j = 0; j < 4; ++j) acc[i][j] = f32x4{0.f, 0.f, 0.f, 0.f};

  for (int k0 = 0; k0 < K; k0 += 32) {
    __syncthreads();
#pragma unroll
    for (int ci = 0; ci < 2; ++ci) {
      const int chunk = w * 2 + ci;
      const int grow = chunk * 16 + srow;
      gload16(&A[(size_t)(m0 + grow) * K + k0 + scol], &As[chunk * 512]);
      gload16(&Bt[(size_t)(n0 + grow) * K + k0 + scol], &Bs[chunk * 512]);
    }
    __syncthreads();
    u16x8 af[4], bf[4];
#pragma unroll
    for (int i = 0; i < 4; ++i)
      af[i] = *(const u16x8*)(&As[(wr * 64 + i * 16 + l15) * 32 + lg * 8]);
#pragma unroll
    for (int j = 0; j < 4; ++j)
      bf[j] = *(const u16x8*)(&Bs[(wc * 64 + j * 16 + l15) * 32 + lg * 8]);
#pragma unroll
    for (int i = 0; i < 4; ++i)
#pragma unroll
      for (int j = 0; j < 4; ++j) acc[i][j] = mfma_bf16(af[i], bf[j], acc[i][j]);
  }

#pragma unroll
  for (int j = 0; j < 4; ++j) {
    int col = n0 + wc * 64 + j * 16 + l15;
    float bv = bias[col];
#pragma unroll
    for (int i = 0; i < 4; ++i) {
#pragma unroll
      for (int r = 0; r < 4; ++r) {
        int row = m0 + wr * 64 + i * 16 + lg * 4 + r;
        float val = acc[i][j][r] + bv;
        if constexpr (std::is_same<OutT, float>::value)
          C[(size_t)row * N + col] = val;
        else
          C[(size_t)row * N + col] = f2bf(val);
      }
    }
  }
}

// ---------------- causal flash attention (4-wave/64-q blocks, grid 1024) ----
// Same compute body as R10 (XOR-swizzled LDS, swapped QK^T, exp2 softmax,
// vote-gated defer-max, dbuf K/V with 1 barrier/tile); geometry refined to
// 4 waves x 16 q-rows (64 q/block), grid 1024 = 4 blocks/CU (LDS 40KB) for
// finer scheduling quanta / better tail packing at the same total wave count.

__global__ __launch_bounds__(256) void attn_kernel(const u16* __restrict__ QKV,
                                                   const u16* __restrict__ Vt,
                                                   u16* __restrict__ O) {
  __shared__ u16 Ks[2][64 * 64];    // 2 x 8KB
  __shared__ u16 Vs[2][64 * 64];    // 2 x 8KB, V^T tile [d=64][k=64]
  __shared__ u16 Ps[4 * 16 * 64];   // per-wave 16-row P / O staging (8KB)

  const int t = threadIdx.x;
  const int lane = t & 63;
  const int w = t >> 6;             // 0..3
  const int l15 = lane & 15, lg = lane >> 4;
  const int xorv = (l15 & 7) << 4;

  // bh->XCD pinning + LPT: per xcd, 4 bh x 32 q-tiles, heaviest first
  const int lid = blockIdx.x;       // 0..1023
  const int xcd = lid & 7;
  const int m = lid >> 3;           // 0..127
  const int bh = (m & 3) * 8 + xcd; // 0..31
  const int qt = 31 - (m >> 2);     // 0..31, heavy first
  const int b = bh >> 4, h = bh & 15;
  const int q0 = qt * 64;
  const int qrow = q0 + w * 16;     // wave's 16 q-rows
  const int nkt = qt + 1;           // k-tiles of 64 (block-uniform)

  const size_t RS = 3 * CDIM;
  const u16* Qp  = QKV + (size_t)(b * TSEQ) * RS + h * DHEAD;
  const u16* Kp  = Qp + CDIM;
  const u16* Vgp = Vt + (size_t)(b * NHEAD + h) * DHEAD * TSEQ;
  char* PwB = (char*)&Ps[w * 16 * 64];

  // Q fragment (B-operand): row q = qrow+l15, k elems lg*8..
  u16x8 qf[2];
#pragma unroll
  for (int c = 0; c < 2; ++c)
    qf[c] = *(const u16x8*)(&Qp[(size_t)(qrow + l15) * RS + c * 32 + lg * 8]);

  f32x4 acc[4];
#pragma unroll
  for (int g = 0; g < 4; ++g) acc[g] = f32x4{0.f, 0.f, 0.f, 0.f};
  float m_run = -3e38f, l_run = 0.f;

  // staging: 256 threads, 2 consecutive 16B chunks each for K and V
  const int sr = t >> 2;            // 0..63
  const int c2 = (t & 3) * 2;       // chunk pair 0,2,4,6
  const int swA0 = sr * 128 + ((c2 * 16) ^ ((sr & 7) << 4));
  const int swA1 = sr * 128 + (((c2 + 1) * 16) ^ ((sr & 7) << 4));

  // prologue: tile0 -> regs -> buf0; tile1 -> regs; one barrier
  u16x8 kreg0 = *(const u16x8*)(&Kp[(size_t)sr * RS + c2 * 8]);
  u16x8 kreg1 = *(const u16x8*)(&Kp[(size_t)sr * RS + c2 * 8 + 8]);
  u16x8 vreg0 = *(const u16x8*)(&Vgp[(size_t)sr * TSEQ + c2 * 8]);
  u16x8 vreg1 = *(const u16x8*)(&Vgp[(size_t)sr * TSEQ + c2 * 8 + 8]);
  *(u16x8*)((char*)Ks[0] + swA0) = kreg0;
  *(u16x8*)((char*)Ks[0] + swA1) = kreg1;
  *(u16x8*)((char*)Vs[0] + swA0) = vreg0;
  *(u16x8*)((char*)Vs[0] + swA1) = vreg1;
  if (nkt > 1) {
    kreg0 = *(const u16x8*)(&Kp[(size_t)(64 + sr) * RS + c2 * 8]);
    kreg1 = *(const u16x8*)(&Kp[(size_t)(64 + sr) * RS + c2 * 8 + 8]);
    vreg0 = *(const u16x8*)(&Vgp[(size_t)sr * TSEQ + 64 + c2 * 8]);
    vreg1 = *(const u16x8*)(&Vgp[(size_t)sr * TSEQ + 64 + c2 * 8 + 8]);
  }
  __syncthreads();

  for (int kb = 0; kb < nkt; ++kb) {
    const int p = kb & 1;
    char* KsB = (char*)Ks[p];
    char* VsB = (char*)Vs[p];

    // write next tile (kb+1, held in regs) into the other buffer
    if (kb + 1 < nkt) {
      *(u16x8*)((char*)Ks[p ^ 1] + swA0) = kreg0;
      *(u16x8*)((char*)Ks[p ^ 1] + swA1) = kreg1;
      *(u16x8*)((char*)Vs[p ^ 1] + swA0) = vreg0;
      *(u16x8*)((char*)Vs[p ^ 1] + swA1) = vreg1;
    }
    // issue loads for kb+2; latency hides under compute below
    if (kb + 2 < nkt) {
      kreg0 = *(const u16x8*)(&Kp[(size_t)((kb + 2) * 64 + sr) * RS + c2 * 8]);
      kreg1 = *(const u16x8*)(&Kp[(size_t)((kb + 2) * 64 + sr) * RS + c2 * 8 + 8]);
      vreg0 = *(const u16x8*)(&Vgp[(size_t)sr * TSEQ + (kb + 2) * 64 + c2 * 8]);
      vreg1 = *(const u16x8*)(&Vgp[(size_t)sr * TSEQ + (kb + 2) * 64 + c2 * 8 + 8]);
    }

    // S^T[k][q]: rows k = f*16+lg*4+r, col q = l15 (pre-scaled by QSCALE)
    f32x4 sfr[4];
    __builtin_amdgcn_s_setprio(1);
#pragma unroll
    for (int f = 0; f < 4; ++f) {
      const char* rowp = KsB + (f * 16 + l15) * 128;
      u16x8 k0 = *(const u16x8*)(rowp + ((lg * 16) ^ xorv));
      u16x8 k1 = *(const u16x8*)(rowp + ((64 + lg * 16) ^ xorv));
      f32x4 s = mfma_bf16(k0, qf[0], f32x4{0.f, 0.f, 0.f, 0.f});
      sfr[f] = mfma_bf16(k1, qf[1], s);
    }
    __builtin_amdgcn_s_setprio(0);

    if (kb * 64 + 63 > qrow) {  // causal mask (wave-uniform predicate)
      const int q_abs = qrow + l15;
#pragma unroll
      for (int f = 0; f < 4; ++f) {
        const int kbase = kb * 64 + f * 16 + lg * 4;
#pragma unroll
        for (int r = 0; r < 4; ++r)
          if (kbase + r > q_abs) sfr[f][r] = -1e9f;
      }
    }

    // row-max: in-lane over 16; wave vote gates rescale (T13, THR=8)
    float mx = sfr[0][0];
#pragma unroll
    for (int f = 0; f < 4; ++f)
#pragma unroll
      for (int r = 0; r < 4; ++r) mx = fmaxf(mx, sfr[f][r]);

    if (__any(mx > m_run + 8.f)) {
      float gm = mx;
      gm = fmaxf(gm, __shfl_xor(gm, 16));
      gm = fmaxf(gm, __shfl_xor(gm, 32));
      float mnew = fmaxf(m_run, gm);
      float fac = exp2f(m_run - mnew);
      m_run = mnew;
      l_run *= fac;
#pragma unroll
      for (int g = 0; g < 4; ++g) acc[g] *= fac;
    }

    // P = exp2(S - m); per-lane partial l; packed b64 -> swizzled Pw
    {
      char* pb = PwB + l15 * 128;
      float ls = 0.f;
#pragma unroll
      for (int f = 0; f < 4; ++f) {
        float p0 = exp2f(sfr[f][0] - m_run);
        float p1 = exp2f(sfr[f][1] - m_run);
        float p2 = exp2f(sfr[f][2] - m_run);
        float p3 = exp2f(sfr[f][3] - m_run);
        ls += (p0 + p1) + (p2 + p3);
        const int boff = (f * 32 + lg * 8) ^ xorv;  // 8B-aligned
        *(uint2*)(pb + boff) = make_uint2(pack2bf(p0, p1), pack2bf(p2, p3));
      }
      l_run += ls;
    }

    // O^T += mfma(V^T, P)
    __builtin_amdgcn_s_setprio(1);
#pragma unroll
    for (int c = 0; c < 2; ++c) {
      const int coff = (c * 64 + lg * 16) ^ xorv;
      u16x8 pf = *(const u16x8*)(PwB + l15 * 128 + coff);
#pragma unroll
      for (int g = 0; g < 4; ++g) {
        u16x8 vf = *(const u16x8*)(VsB + (g * 16 + l15) * 128 + coff);
        acc[g] = mfma_bf16(vf, pf, acc[g]);
      }
    }
    __builtin_amdgcn_s_setprio(0);

    __syncthreads();  // single barrier per k-tile
  }

  // epilogue: reduce l across lane-groups, normalize, un-transpose via Pw
  float lt = l_run;
  lt += __shfl_xor(lt, 16);
  lt += __shfl_xor(lt, 32);
  float inv = 1.f / lt;
  {
    char* pb = PwB + l15 * 128;
#pragma unroll
    for (int g = 0; g < 4; ++g) {
      const int boff = (g * 32 + lg * 8) ^ xorv;
      *(uint2*)(pb + boff) = make_uint2(pack2bf(acc[g][0] * inv, acc[g][1] * inv),
                                        pack2bf(acc[g][2] * inv, acc[g][3] * inv));
    }
  }
#pragma unroll
  for (int i = 0; i < 2; ++i) {
    const int rl = i * 8 + (lane >> 3);  // 0..15
    const int ch = lane & 7;
    u16x8 vv = *(const u16x8*)(PwB + rl * 128 + ((ch * 16) ^ ((rl & 7) << 4)));
    *(u16x8*)(&O[(size_t)(b * TSEQ + qrow + rl) * CDIM + h * DHEAD + ch * 8]) = vv;
  }
}

// ---------------- launch ----------------

extern "C" void kernel_launch(void* const* d_in, const int* in_sizes, int n_in,
                              void* d_out, int out_size, void* d_ws, size_t ws_size,
                              hipStream_t stream) {
  const float* x  = (const float*)d_in[0];
  const float* wq = (const float*)d_in[1];
  const float* bq = (const float*)d_in[2];
  const float* wk = (const float*)d_in[3];
  const float* bk = (const float*)d_in[4];
  const float* wv = (const float*)d_in[5];
  const float* bv = (const float*)d_in[6];
  const float* wo = (const float*)d_in[7];
  const float* bo = (const float*)d_in[8];
  float* out = (float*)d_out;

  char* ws = (char*)d_ws;
  u16*  xb      = (u16*)(ws);                 // 8MB; dead after QKV GEMM
  u16*  Vtg     = (u16*)(ws);                 // aliases xb (written after)
  u16*  wqkvT   = (u16*)(ws + (8ll << 20));
  u16*  woT     = (u16*)(ws + (14ll << 20));
  u16*  QKV     = (u16*)(ws + (16ll << 20));
  u16*  Obuf    = (u16*)(ws + (40ll << 20));
  float* biasqkv = (float*)(ws + (48ll << 20));

  cast_x_kernel<<<(NROWS * CDIM / 4 + 255) / 256, 256, 0, stream>>>(x, xb, NROWS * CDIM / 4);
  {
    dim3 g(CDIM / 32, CDIM / 32, 4), blk(32, 8);
    transpose_cast_kernel<<<g, blk, 0, stream>>>(wq, wk, wv, wo, wqkvT, woT);
  }
  bias_concat_kernel<<<12, 256, 0, stream>>>(bq, bk, bv, biasqkv);
  gemm_bt_kernel<u16><<<(NROWS / 128) * ((3 * CDIM) / 128), 256, 0, stream>>>(
      xb, wqkvT, biasqkv, QKV, NROWS, 3 * CDIM, CDIM, NROWS / 128);
  {
    dim3 g(TSEQ / 32, DHEAD / 32, BATCH * NHEAD), blk(32, 8);
    vtrans_kernel<<<g, blk, 0, stream>>>(QKV, Vtg);
  }
  attn_kernel<<<1024, 256, 0, stream>>>(QKV, Vtg, Obuf);
  gemm_bt_kernel<float><<<(NROWS / 128) * (CDIM / 128), 256, 0, stream>>>(
      Obuf, woT, bo, out, NROWS, CDIM, CDIM, NROWS / 128);
}

// Round 12
// 130.727 us; speedup vs baseline: 1.0734x; 1.0222x over previous
//
#include <hip/hip_runtime.h>
#include <cstdint>
#include <type_traits>

// GPT MHA forward. B=2, T=2048, C=1024, H=16, d=64.
// cast x->bf16 | transpose weights (wq pre-scaled 0.125*log2e) | bias concat
// | QKV GEMM (128x128, BK=32, gload_lds) | V-transpose
// | causal flash attn (4 waves x 16 q-rows, 64 q/block, grid 1024, dbuf K/V,
//   T15 S-lookahead: QK^T(k+1) overlaps softmax(k)+PV(k), v_max3 tree,
//   XOR-swizzled LDS, swapped QK^T, exp2 softmax, defer-max, XCD pin + LPT)
// | out-proj GEMM.

#define TSEQ  2048
#define BATCH 2
#define CDIM  1024
#define NHEAD 16
#define DHEAD 64
#define NROWS (BATCH * TSEQ)  // 4096

// 0.125 (1/sqrt(d)) * log2(e): folded into wq/bq so softmax uses exp2
#define QSCALE 0.1803368801111244f

typedef unsigned short u16;
typedef u16   u16x8  __attribute__((ext_vector_type(8)));
typedef __bf16 bf16x8 __attribute__((ext_vector_type(8)));
typedef __bf16 bf16x2 __attribute__((ext_vector_type(2)));
typedef float f32x4  __attribute__((ext_vector_type(4)));

typedef const __attribute__((address_space(1))) void* gas_vp;
typedef __attribute__((address_space(3))) void* las_vp;

__device__ __forceinline__ u16 f2bf(float f) {
  return __builtin_bit_cast(u16, (__bf16)f);
}

__device__ __forceinline__ uint32_t pack2bf(float a, float b) {
  bf16x2 v;
  v[0] = (__bf16)a;
  v[1] = (__bf16)b;
  return __builtin_bit_cast(uint32_t, v);
}

__device__ __forceinline__ float max3f(float a, float b, float c) {
  return fmaxf(fmaxf(a, b), c);  // clang fuses to v_max3_f32
}

__device__ __forceinline__ f32x4 mfma_bf16(u16x8 a, u16x8 b, f32x4 c) {
  return __builtin_amdgcn_mfma_f32_16x16x32_bf16(
      __builtin_bit_cast(bf16x8, a), __builtin_bit_cast(bf16x8, b), c, 0, 0, 0);
}

__device__ __forceinline__ void gload16(const u16* g, u16* l) {
  __builtin_amdgcn_global_load_lds((gas_vp)g, (las_vp)l, 16, 0, 0);
}

// ---------------- prep kernels ----------------

__global__ __launch_bounds__(256) void cast_x_kernel(const float* __restrict__ in,
                                                     u16* __restrict__ out, int n4) {
  int i = blockIdx.x * 256 + threadIdx.x;
  if (i < n4) {
    float4 v = ((const float4*)in)[i];
    ((uint2*)out)[i] = make_uint2(pack2bf(v.x, v.y), pack2bf(v.z, v.w));
  }
}

__global__ __launch_bounds__(256) void transpose_cast_kernel(
    const float* __restrict__ w0, const float* __restrict__ w1,
    const float* __restrict__ w2, const float* __restrict__ w3,
    u16* __restrict__ outQKV, u16* __restrict__ outO) {
  __shared__ float tile[32][33];
  const int m = blockIdx.z;
  const float* w = (m == 0) ? w0 : (m == 1) ? w1 : (m == 2) ? w2 : w3;
  const float scale = (m == 0) ? QSCALE : 1.0f;
  u16* out = (m < 3) ? (outQKV + (size_t)m * CDIM * CDIM) : outO;
  const int n0 = blockIdx.x * 32;
  const int k0 = blockIdx.y * 32;
  const int tx = threadIdx.x, ty = threadIdx.y;  // block (32, 8)
#pragma unroll
  for (int i = 0; i < 4; ++i)
    tile[ty + i * 8][tx] = w[(size_t)(k0 + ty + i * 8) * CDIM + n0 + tx];
  __syncthreads();
#pragma unroll
  for (int i = 0; i < 4; ++i)
    out[(size_t)(n0 + ty + i * 8) * CDIM + k0 + tx] = f2bf(tile[tx][ty + i * 8] * scale);
}

__global__ __launch_bounds__(256) void bias_concat_kernel(const float* __restrict__ bq,
                                                          const float* __restrict__ bk,
                                                          const float* __restrict__ bv,
                                                          float* __restrict__ out) {
  int i = blockIdx.x * 256 + threadIdx.x;
  if (i < 3 * CDIM) {
    float v = (i < CDIM) ? bq[i] * QSCALE
            : (i < 2 * CDIM) ? bk[i - CDIM] : bv[i - 2 * CDIM];
    out[i] = v;
  }
}

// V part of QKV [B*T][3C] -> Vt [B][H][D][T]
__global__ __launch_bounds__(256) void vtrans_kernel(const u16* __restrict__ QKV,
                                                     u16* __restrict__ Vt) {
  __shared__ u16 tile[32][33];
  const int bh = blockIdx.z;
  const int b = bh >> 4, h = bh & 15;
  const int t0 = blockIdx.x * 32, d0 = blockIdx.y * 32;
  const int tx = threadIdx.x, ty = threadIdx.y;  // block (32, 8)
#pragma unroll
  for (int i = 0; i < 4; ++i)
    tile[ty + i * 8][tx] =
        QKV[(size_t)(b * TSEQ + t0 + ty + i * 8) * (3 * CDIM) + 2 * CDIM + h * DHEAD + d0 + tx];
  __syncthreads();
#pragma unroll
  for (int i = 0; i < 4; ++i)
    Vt[(size_t)((b * NHEAD + h) * DHEAD + d0 + ty + i * 8) * TSEQ + t0 + tx] =
        tile[tx][ty + i * 8];
}

// ---------------- GEMM: C[M][N] = A[M][K] @ Bt[N][K]^T + bias ----------------
// 128x128 tile, BK=32, 4 waves, global_load_lds staging; 1D grid + XCD swizzle.

template <typename OutT>
__global__ __launch_bounds__(256) void gemm_bt_kernel(
    const u16* __restrict__ A, const u16* __restrict__ Bt,
    const float* __restrict__ bias, OutT* __restrict__ C,
    int M, int N, int K, int mblocks) {
  __shared__ u16 As[128 * 32];
  __shared__ u16 Bs[128 * 32];
  const int nwg = gridDim.x;
  const int lid = blockIdx.x;
  const int swz = (lid & 7) * (nwg >> 3) + (lid >> 3);
  const int m0 = (swz % mblocks) * 128;
  const int n0 = (swz / mblocks) * 128;

  const int t = threadIdx.x;
  const int lane = t & 63;
  const int w = t >> 6;
  const int wr = w >> 1, wc = w & 1;
  const int l15 = lane & 15;
  const int lg = lane >> 4;
  const int srow = lane >> 2;
  const int scol = (lane & 3) * 8;

  f32x4 acc[4][4];
#pragma unroll
  for (int i = 0; i < 4; ++i)
#pragma unroll
    for (int j = 0; j < 4; ++j) acc[i][j] = f32x4{0.f, 0.f, 0.f, 0.f};

  for (int k0 = 0; k0 < K; k0 += 32) {
    __syncthreads();
#pragma unroll
    for (int ci = 0; ci < 2; ++ci) {
      const int chunk = w * 2 + ci;
      const int grow = chunk * 16 + srow;
      gload16(&A[(size_t)(m0 + grow) * K + k0 + scol], &As[chunk * 512]);
      gload16(&Bt[(size_t)(n0 + grow) * K + k0 + scol], &Bs[chunk * 512]);
    }
    __syncthreads();
    u16x8 af[4], bf[4];
#pragma unroll
    for (int i = 0; i < 4; ++i)
      af[i] = *(const u16x8*)(&As[(wr * 64 + i * 16 + l15) * 32 + lg * 8]);
#pragma unroll
    for (int j = 0; j < 4; ++j)
      bf[j] = *(const u16x8*)(&Bs[(wc * 64 + j * 16 + l15) * 32 + lg * 8]);
#pragma unroll
    for (int i = 0; i < 4; ++i)
#pragma unroll
      for (int j = 0; j < 4; ++j) acc[i][j] = mfma_bf16(af[i], bf[j], acc[i][j]);
  }

#pragma unroll
  for (int j = 0; j < 4; ++j) {
    int col = n0 + wc * 64 + j * 16 + l15;
    float bv = bias[col];
#pragma unroll
    for (int i = 0; i < 4; ++i) {
#pragma unroll
      for (int r = 0; r < 4; ++r) {
        int row = m0 + wr * 64 + i * 16 + lg * 4 + r;
        float val = acc[i][j][r] + bv;
        if constexpr (std::is_same<OutT, float>::value)
          C[(size_t)row * N + col] = val;
        else
          C[(size_t)row * N + col] = f2bf(val);
      }
    }
  }
}

// ---------------- causal flash attention (T15 S-lookahead) ----------------
// 4 waves x 16 q-rows (64 q/block), grid 1024, dbuf K/V. Loop invariant:
// S(kb) already in regs. Body: {write regs(kb+1)->buf^1; load kb+2->regs;
// barrier; QK^T(kb+1) [MFMA] || mask+softmax(kb)+PV(kb) [VALU+MFMA]; barrier}.
// The next tile's QK^T issues before the softmax chain -> matrix pipe stays
// fed while VALU walks fmax/exp2. v_max3 tree for row-max.

__global__ __launch_bounds__(256) void attn_kernel(const u16* __restrict__ QKV,
                                                   const u16* __restrict__ Vt,
                                                   u16* __restrict__ O) {
  __shared__ u16 Ks[2][64 * 64];    // 2 x 8KB
  __shared__ u16 Vs[2][64 * 64];    // 2 x 8KB, V^T tile [d=64][k=64]
  __shared__ u16 Ps[4 * 16 * 64];   // per-wave 16-row P / O staging (8KB)

  const int t = threadIdx.x;
  const int lane = t & 63;
  const int w = t >> 6;             // 0..3
  const int l15 = lane & 15, lg = lane >> 4;
  const int xorv = (l15 & 7) << 4;

  // bh->XCD pinning + LPT: per xcd, 4 bh x 32 q-tiles, heaviest first
  const int lid = blockIdx.x;       // 0..1023
  const int xcd = lid & 7;
  const int m = lid >> 3;           // 0..127
  const int bh = (m & 3) * 8 + xcd; // 0..31
  const int qt = 31 - (m >> 2);     // 0..31, heavy first
  const int b = bh >> 4, h = bh & 15;
  const int q0 = qt * 64;
  const int qrow = q0 + w * 16;     // wave's 16 q-rows
  const int nkt = qt + 1;           // k-tiles of 64 (block-uniform)

  const size_t RS = 3 * CDIM;
  const u16* Qp  = QKV + (size_t)(b * TSEQ) * RS + h * DHEAD;
  const u16* Kp  = Qp + CDIM;
  const u16* Vgp = Vt + (size_t)(b * NHEAD + h) * DHEAD * TSEQ;
  char* PwB = (char*)&Ps[w * 16 * 64];

  // Q fragment (B-operand): row q = qrow+l15, k elems lg*8..
  u16x8 qf[2];
#pragma unroll
  for (int c = 0; c < 2; ++c)
    qf[c] = *(const u16x8*)(&Qp[(size_t)(qrow + l15) * RS + c * 32 + lg * 8]);

  f32x4 acc[4];
#pragma unroll
  for (int g = 0; g < 4; ++g) acc[g] = f32x4{0.f, 0.f, 0.f, 0.f};
  float m_run = -3e38f, l_run = 0.f;

  // staging: 256 threads, 2 consecutive 16B chunks each for K and V
  const int sr = t >> 2;            // 0..63
  const int c2 = (t & 3) * 2;       // chunk pair 0,2,4,6
  const int swA0 = sr * 128 + ((c2 * 16) ^ ((sr & 7) << 4));
  const int swA1 = sr * 128 + (((c2 + 1) * 16) ^ ((sr & 7) << 4));

  // prologue: tile0 -> buf0; tile1 -> regs; barrier; S(0) = QK^T(buf0)
  u16x8 kreg0 = *(const u16x8*)(&Kp[(size_t)sr * RS + c2 * 8]);
  u16x8 kreg1 = *(const u16x8*)(&Kp[(size_t)sr * RS + c2 * 8 + 8]);
  u16x8 vreg0 = *(const u16x8*)(&Vgp[(size_t)sr * TSEQ + c2 * 8]);
  u16x8 vreg1 = *(const u16x8*)(&Vgp[(size_t)sr * TSEQ + c2 * 8 + 8]);
  *(u16x8*)((char*)Ks[0] + swA0) = kreg0;
  *(u16x8*)((char*)Ks[0] + swA1) = kreg1;
  *(u16x8*)((char*)Vs[0] + swA0) = vreg0;
  *(u16x8*)((char*)Vs[0] + swA1) = vreg1;
  if (nkt > 1) {
    kreg0 = *(const u16x8*)(&Kp[(size_t)(64 + sr) * RS + c2 * 8]);
    kreg1 = *(const u16x8*)(&Kp[(size_t)(64 + sr) * RS + c2 * 8 + 8]);
    vreg0 = *(const u16x8*)(&Vgp[(size_t)sr * TSEQ + 64 + c2 * 8]);
    vreg1 = *(const u16x8*)(&Vgp[(size_t)sr * TSEQ + 64 + c2 * 8 + 8]);
  }
  __syncthreads();

  f32x4 sfr[4];
#pragma unroll
  for (int f = 0; f < 4; ++f) {
    const char* rowp = (char*)Ks[0] + (f * 16 + l15) * 128;
    u16x8 k0 = *(const u16x8*)(rowp + ((lg * 16) ^ xorv));
    u16x8 k1 = *(const u16x8*)(rowp + ((64 + lg * 16) ^ xorv));
    f32x4 s = mfma_bf16(k0, qf[0], f32x4{0.f, 0.f, 0.f, 0.f});
    sfr[f] = mfma_bf16(k1, qf[1], s);
  }

  for (int kb = 0; kb < nkt; ++kb) {
    const int p = kb & 1;
    char* VsB = (char*)Vs[p];

    // write next tile (kb+1) into the other buffer; issue loads for kb+2
    if (kb + 1 < nkt) {
      *(u16x8*)((char*)Ks[p ^ 1] + swA0) = kreg0;
      *(u16x8*)((char*)Ks[p ^ 1] + swA1) = kreg1;
      *(u16x8*)((char*)Vs[p ^ 1] + swA0) = vreg0;
      *(u16x8*)((char*)Vs[p ^ 1] + swA1) = vreg1;
    }
    if (kb + 2 < nkt) {
      kreg0 = *(const u16x8*)(&Kp[(size_t)((kb + 2) * 64 + sr) * RS + c2 * 8]);
      kreg1 = *(const u16x8*)(&Kp[(size_t)((kb + 2) * 64 + sr) * RS + c2 * 8 + 8]);
      vreg0 = *(const u16x8*)(&Vgp[(size_t)sr * TSEQ + (kb + 2) * 64 + c2 * 8]);
      vreg1 = *(const u16x8*)(&Vgp[(size_t)sr * TSEQ + (kb + 2) * 64 + c2 * 8 + 8]);
    }
    __syncthreads();  // buf[p^1]=kb+1 ready; buf[p] (V of kb) still intact

    // --- lookahead: S(kb+1) = QK^T from buf[p^1] (MFMA pipe, independent) ---
    f32x4 snx[4];
    if (kb + 1 < nkt) {
      __builtin_amdgcn_s_setprio(1);
#pragma unroll
      for (int f = 0; f < 4; ++f) {
        const char* rowp = (char*)Ks[p ^ 1] + (f * 16 + l15) * 128;
        u16x8 k0 = *(const u16x8*)(rowp + ((lg * 16) ^ xorv));
        u16x8 k1 = *(const u16x8*)(rowp + ((64 + lg * 16) ^ xorv));
        f32x4 s = mfma_bf16(k0, qf[0], f32x4{0.f, 0.f, 0.f, 0.f});
        snx[f] = mfma_bf16(k1, qf[1], s);
      }
      __builtin_amdgcn_s_setprio(0);
    }

    // --- consume S(kb): mask, softmax, PV (VALU + MFMA) ---
    if (kb * 64 + 63 > qrow) {  // causal mask (wave-uniform predicate)
      const int q_abs = qrow + l15;
#pragma unroll
      for (int f = 0; f < 4; ++f) {
        const int kbase = kb * 64 + f * 16 + lg * 4;
#pragma unroll
        for (int r = 0; r < 4; ++r)
          if (kbase + r > q_abs) sfr[f][r] = -1e9f;
      }
    }

    // row-max via v_max3 tree (depth ~4); wave vote gates rescale (T13)
    float t0 = max3f(sfr[0][0], sfr[0][1], sfr[0][2]);
    float t1 = max3f(sfr[0][3], sfr[1][0], sfr[1][1]);
    float t2 = max3f(sfr[1][2], sfr[1][3], sfr[2][0]);
    float t3 = max3f(sfr[2][1], sfr[2][2], sfr[2][3]);
    float t4 = max3f(sfr[3][0], sfr[3][1], sfr[3][2]);
    float mx = fmaxf(max3f(t0, t1, t2), max3f(t3, t4, sfr[3][3]));

    if (__any(mx > m_run + 8.f)) {
      float gm = mx;
      gm = fmaxf(gm, __shfl_xor(gm, 16));
      gm = fmaxf(gm, __shfl_xor(gm, 32));
      float mnew = fmaxf(m_run, gm);
      float fac = exp2f(m_run - mnew);
      m_run = mnew;
      l_run *= fac;
#pragma unroll
      for (int g = 0; g < 4; ++g) acc[g] *= fac;
    }

    // P = exp2(S - m); per-lane partial l; packed b64 -> swizzled Pw
    {
      char* pb = PwB + l15 * 128;
      float ls = 0.f;
#pragma unroll
      for (int f = 0; f < 4; ++f) {
        float p0 = exp2f(sfr[f][0] - m_run);
        float p1 = exp2f(sfr[f][1] - m_run);
        float p2 = exp2f(sfr[f][2] - m_run);
        float p3 = exp2f(sfr[f][3] - m_run);
        ls += (p0 + p1) + (p2 + p3);
        const int boff = (f * 32 + lg * 8) ^ xorv;  // 8B-aligned
        *(uint2*)(pb + boff) = make_uint2(pack2bf(p0, p1), pack2bf(p2, p3));
      }
      l_run += ls;
    }

    // O^T += mfma(V^T, P) from buf[p]
    __builtin_amdgcn_s_setprio(1);
#pragma unroll
    for (int c = 0; c < 2; ++c) {
      const int coff = (c * 64 + lg * 16) ^ xorv;
      u16x8 pf = *(const u16x8*)(PwB + l15 * 128 + coff);
#pragma unroll
      for (int g = 0; g < 4; ++g) {
        u16x8 vf = *(const u16x8*)(VsB + (g * 16 + l15) * 128 + coff);
        acc[g] = mfma_bf16(vf, pf, acc[g]);
      }
    }
    __builtin_amdgcn_s_setprio(0);

    __syncthreads();  // all reads of buf[p] done -> next iter may overwrite

#pragma unroll
    for (int f = 0; f < 4; ++f) sfr[f] = snx[f];
  }

  // epilogue: reduce l across lane-groups, normalize, un-transpose via Pw
  float lt = l_run;
  lt += __shfl_xor(lt, 16);
  lt += __shfl_xor(lt, 32);
  float inv = 1.f / lt;
  {
    char* pb = PwB + l15 * 128;
#pragma unroll
    for (int g = 0; g < 4; ++g) {
      const int boff = (g * 32 + lg * 8) ^ xorv;
      *(uint2*)(pb + boff) = make_uint2(pack2bf(acc[g][0] * inv, acc[g][1] * inv),
                                        pack2bf(acc[g][2] * inv, acc[g][3] * inv));
    }
  }
#pragma unroll
  for (int i = 0; i < 2; ++i) {
    const int rl = i * 8 + (lane >> 3);  // 0..15
    const int ch = lane & 7;
    u16x8 vv = *(const u16x8*)(PwB + rl * 128 + ((ch * 16) ^ ((rl & 7) << 4)));
    *(u16x8*)(&O[(size_t)(b * TSEQ + qrow + rl) * CDIM + h * DHEAD + ch * 8]) = vv;
  }
}

// ---------------- launch ----------------

extern "C" void kernel_launch(void* const* d_in, const int* in_sizes, int n_in,
                              void* d_out, int out_size, void* d_ws, size_t ws_size,
                              hipStream_t stream) {
  const float* x  = (const float*)d_in[0];
  const float* wq = (const float*)d_in[1];
  const float* bq = (const float*)d_in[2];
  const float* wk = (const float*)d_in[3];
  const float* bk = (const float*)d_in[4];
  const float* wv = (const float*)d_in[5];
  const float* bv = (const float*)d_in[6];
  const float* wo = (const float*)d_in[7];
  const float* bo = (const float*)d_in[8];
  float* out = (float*)d_out;

  char* ws = (char*)d_ws;
  u16*  xb      = (u16*)(ws);                 // 8MB; dead after QKV GEMM
  u16*  Vtg     = (u16*)(ws);                 // aliases xb (written after)
  u16*  wqkvT   = (u16*)(ws + (8ll << 20));
  u16*  woT     = (u16*)(ws + (14ll << 20));
  u16*  QKV     = (u16*)(ws + (16ll << 20));
  u16*  Obuf    = (u16*)(ws + (40ll << 20));
  float* biasqkv = (float*)(ws + (48ll << 20));

  cast_x_kernel<<<(NROWS * CDIM / 4 + 255) / 256, 256, 0, stream>>>(x, xb, NROWS * CDIM / 4);
  {
    dim3 g(CDIM / 32, CDIM / 32, 4), blk(32, 8);
    transpose_cast_kernel<<<g, blk, 0, stream>>>(wq, wk, wv, wo, wqkvT, woT);
  }
  bias_concat_kernel<<<12, 256, 0, stream>>>(bq, bk, bv, biasqkv);
  gemm_bt_kernel<u16><<<(NROWS / 128) * ((3 * CDIM) / 128), 256, 0, stream>>>(
      xb, wqkvT, biasqkv, QKV, NROWS, 3 * CDIM, CDIM, NROWS / 128);
  {
    dim3 g(TSEQ / 32, DHEAD / 32, BATCH * NHEAD), blk(32, 8);
    vtrans_kernel<<<g, blk, 0, stream>>>(QKV, Vtg);
  }
  attn_kernel<<<1024, 256, 0, stream>>>(QKV, Vtg, Obuf);
  gemm_bt_kernel<float><<<(NROWS / 128) * (CDIM / 128), 256, 0, stream>>>(
      Obuf, woT, bo, out, NROWS, CDIM, CDIM, NROWS / 128);
}

// Round 13
// 122.815 us; speedup vs baseline: 1.1426x; 1.0644x over previous
//
#include <hip/hip_runtime.h>
#include <cstdint>
#include <type_traits>

// GPT MHA forward. B=2, T=2048, C=1024, H=16, d=64.
// cast x->bf16 | transpose weights (wq pre-scaled 0.125*log2e) | bias concat
// | QKV GEMM (128x128, BK=32, gload_lds, 2-PHASE dbuf, 2D-XCD L2 tiling)
// | V-transpose | causal flash attn (frozen R12: 4 waves x 16 q-rows, dbuf,
//   T15 S-lookahead, XOR-swizzle, swapped QK^T, exp2, defer-max, XCD pin)
// | out-proj GEMM (same 2-phase structure).

#define TSEQ  2048
#define BATCH 2
#define CDIM  1024
#define NHEAD 16
#define DHEAD 64
#define NROWS (BATCH * TSEQ)  // 4096

// 0.125 (1/sqrt(d)) * log2(e): folded into wq/bq so softmax uses exp2
#define QSCALE 0.1803368801111244f

typedef unsigned short u16;
typedef u16   u16x8  __attribute__((ext_vector_type(8)));
typedef __bf16 bf16x8 __attribute__((ext_vector_type(8)));
typedef __bf16 bf16x2 __attribute__((ext_vector_type(2)));
typedef float f32x4  __attribute__((ext_vector_type(4)));

typedef const __attribute__((address_space(1))) void* gas_vp;
typedef __attribute__((address_space(3))) void* las_vp;

__device__ __forceinline__ u16 f2bf(float f) {
  return __builtin_bit_cast(u16, (__bf16)f);
}

__device__ __forceinline__ uint32_t pack2bf(float a, float b) {
  bf16x2 v;
  v[0] = (__bf16)a;
  v[1] = (__bf16)b;
  return __builtin_bit_cast(uint32_t, v);
}

__device__ __forceinline__ float max3f(float a, float b, float c) {
  return fmaxf(fmaxf(a, b), c);  // clang fuses to v_max3_f32
}

__device__ __forceinline__ f32x4 mfma_bf16(u16x8 a, u16x8 b, f32x4 c) {
  return __builtin_amdgcn_mfma_f32_16x16x32_bf16(
      __builtin_bit_cast(bf16x8, a), __builtin_bit_cast(bf16x8, b), c, 0, 0, 0);
}

__device__ __forceinline__ void gload16(const u16* g, u16* l) {
  __builtin_amdgcn_global_load_lds((gas_vp)g, (las_vp)l, 16, 0, 0);
}

// ---------------- prep kernels ----------------

__global__ __launch_bounds__(256) void cast_x_kernel(const float* __restrict__ in,
                                                     u16* __restrict__ out, int n4) {
  int i = blockIdx.x * 256 + threadIdx.x;
  if (i < n4) {
    float4 v = ((const float4*)in)[i];
    ((uint2*)out)[i] = make_uint2(pack2bf(v.x, v.y), pack2bf(v.z, v.w));
  }
}

__global__ __launch_bounds__(256) void transpose_cast_kernel(
    const float* __restrict__ w0, const float* __restrict__ w1,
    const float* __restrict__ w2, const float* __restrict__ w3,
    u16* __restrict__ outQKV, u16* __restrict__ outO) {
  __shared__ float tile[32][33];
  const int m = blockIdx.z;
  const float* w = (m == 0) ? w0 : (m == 1) ? w1 : (m == 2) ? w2 : w3;
  const float scale = (m == 0) ? QSCALE : 1.0f;
  u16* out = (m < 3) ? (outQKV + (size_t)m * CDIM * CDIM) : outO;
  const int n0 = blockIdx.x * 32;
  const int k0 = blockIdx.y * 32;
  const int tx = threadIdx.x, ty = threadIdx.y;  // block (32, 8)
#pragma unroll
  for (int i = 0; i < 4; ++i)
    tile[ty + i * 8][tx] = w[(size_t)(k0 + ty + i * 8) * CDIM + n0 + tx];
  __syncthreads();
#pragma unroll
  for (int i = 0; i < 4; ++i)
    out[(size_t)(n0 + ty + i * 8) * CDIM + k0 + tx] = f2bf(tile[tx][ty + i * 8] * scale);
}

__global__ __launch_bounds__(256) void bias_concat_kernel(const float* __restrict__ bq,
                                                          const float* __restrict__ bk,
                                                          const float* __restrict__ bv,
                                                          float* __restrict__ out) {
  int i = blockIdx.x * 256 + threadIdx.x;
  if (i < 3 * CDIM) {
    float v = (i < CDIM) ? bq[i] * QSCALE
            : (i < 2 * CDIM) ? bk[i - CDIM] : bv[i - 2 * CDIM];
    out[i] = v;
  }
}

// V part of QKV [B*T][3C] -> Vt [B][H][D][T]
__global__ __launch_bounds__(256) void vtrans_kernel(const u16* __restrict__ QKV,
                                                     u16* __restrict__ Vt) {
  __shared__ u16 tile[32][33];
  const int bh = blockIdx.z;
  const int b = bh >> 4, h = bh & 15;
  const int t0 = blockIdx.x * 32, d0 = blockIdx.y * 32;
  const int tx = threadIdx.x, ty = threadIdx.y;  // block (32, 8)
#pragma unroll
  for (int i = 0; i < 4; ++i)
    tile[ty + i * 8][tx] =
        QKV[(size_t)(b * TSEQ + t0 + ty + i * 8) * (3 * CDIM) + 2 * CDIM + h * DHEAD + d0 + tx];
  __syncthreads();
#pragma unroll
  for (int i = 0; i < 4; ++i)
    Vt[(size_t)((b * NHEAD + h) * DHEAD + d0 + ty + i * 8) * TSEQ + t0 + tx] =
        tile[tx][ty + i * 8];
}

// ---------------- GEMM: C[M][N] = A[M][K] @ Bt[N][K]^T + bias ----------------
// 128x128 tile, BK=32, 4 waves, gload_lds. 2-PHASE: stage(t+1) issued BEFORE
// compute(t); one __syncthreads per K-tile (its vmcnt(0) drain overlaps with
// the compute just done). 2D XCD tiling: XCD x = (xr=x&3, xc=x>>2) owns
// m-panels [8xr, 8xr+8) x n-half xc; n-outer order -> A-group (2MB) + B-tile
// (256KB) stay L2-resident. M/128 must be 32; nb = N/128 must be even.

template <typename OutT>
__global__ __launch_bounds__(256) void gemm_bt_kernel(
    const u16* __restrict__ A, const u16* __restrict__ Bt,
    const float* __restrict__ bias, OutT* __restrict__ C,
    int M, int N, int K, int nb) {
  __shared__ u16 As[2][128 * 32];
  __shared__ u16 Bs[2][128 * 32];

  // 2D XCD decode: lid&7 = XCD; within XCD, n-outer x 8 m-blocks
  const int lid = blockIdx.x;
  const int x = lid & 7;
  const int xr = x & 3, xc = x >> 2;
  const int r = lid >> 3;           // 0 .. 4*nb-1
  const int nloc = r >> 3;          // 0 .. nb/2-1
  const int mloc = r & 7;           // 0 .. 7
  const int m0 = (xr * 8 + mloc) * 128;
  const int n0 = (xc * (nb >> 1) + nloc) * 128;

  const int t = threadIdx.x;
  const int lane = t & 63;
  const int w = t >> 6;
  const int wr = w >> 1, wc = w & 1;
  const int l15 = lane & 15;
  const int lg = lane >> 4;
  const int srow = lane >> 2;
  const int scol = (lane & 3) * 8;

  f32x4 acc[4][4];
#pragma unroll
  for (int i = 0; i < 4; ++i)
#pragma unroll
    for (int j = 0; j < 4; ++j) acc[i][j] = f32x4{0.f, 0.f, 0.f, 0.f};

  const int NK = K >> 5;  // K-tiles of 32

  // prologue: tile 0 -> buf 0
#pragma unroll
  for (int ci = 0; ci < 2; ++ci) {
    const int chunk = w * 2 + ci;
    const int grow = chunk * 16 + srow;
    gload16(&A[(size_t)(m0 + grow) * K + scol], &As[0][chunk * 512]);
    gload16(&Bt[(size_t)(n0 + grow) * K + scol], &Bs[0][chunk * 512]);
  }
  __syncthreads();  // drains vmcnt -> tile 0 ready

  for (int it = 0; it < NK; ++it) {
    const int cur = it & 1;
    // issue next-tile stage BEFORE compute (2-phase essence)
    if (it + 1 < NK) {
      const int k0 = (it + 1) * 32;
#pragma unroll
      for (int ci = 0; ci < 2; ++ci) {
        const int chunk = w * 2 + ci;
        const int grow = chunk * 16 + srow;
        gload16(&A[(size_t)(m0 + grow) * K + k0 + scol], &As[cur ^ 1][chunk * 512]);
        gload16(&Bt[(size_t)(n0 + grow) * K + k0 + scol], &Bs[cur ^ 1][chunk * 512]);
      }
    }
    // compute current tile
    u16x8 af[4], bf[4];
#pragma unroll
    for (int i = 0; i < 4; ++i)
      af[i] = *(const u16x8*)(&As[cur][(wr * 64 + i * 16 + l15) * 32 + lg * 8]);
#pragma unroll
    for (int j = 0; j < 4; ++j)
      bf[j] = *(const u16x8*)(&Bs[cur][(wc * 64 + j * 16 + l15) * 32 + lg * 8]);
    __builtin_amdgcn_s_setprio(1);
#pragma unroll
    for (int i = 0; i < 4; ++i)
#pragma unroll
      for (int j = 0; j < 4; ++j) acc[i][j] = mfma_bf16(af[i], bf[j], acc[i][j]);
    __builtin_amdgcn_s_setprio(0);
    __syncthreads();  // single barrier/tile: drains next tile's loads too
  }

#pragma unroll
  for (int j = 0; j < 4; ++j) {
    int col = n0 + wc * 64 + j * 16 + l15;
    float bv = bias[col];
#pragma unroll
    for (int i = 0; i < 4; ++i) {
#pragma unroll
      for (int r2 = 0; r2 < 4; ++r2) {
        int row = m0 + wr * 64 + i * 16 + lg * 4 + r2;
        float val = acc[i][j][r2] + bv;
        if constexpr (std::is_same<OutT, float>::value)
          C[(size_t)row * N + col] = val;
        else
          C[(size_t)row * N + col] = f2bf(val);
      }
    }
  }
}

// ---------------- causal flash attention (frozen R12) ----------------
// 4 waves x 16 q-rows (64 q/block), grid 1024, dbuf K/V, T15 S-lookahead:
// QK^T(kb+1) overlaps softmax(kb)+PV(kb). v_max3 tree, XOR-swizzled LDS,
// swapped QK^T, exp2 softmax, vote-gated defer-max, bh->XCD pin + LPT.

__global__ __launch_bounds__(256) void attn_kernel(const u16* __restrict__ QKV,
                                                   const u16* __restrict__ Vt,
                                                   u16* __restrict__ O) {
  __shared__ u16 Ks[2][64 * 64];    // 2 x 8KB
  __shared__ u16 Vs[2][64 * 64];    // 2 x 8KB, V^T tile [d=64][k=64]
  __shared__ u16 Ps[4 * 16 * 64];   // per-wave 16-row P / O staging (8KB)

  const int t = threadIdx.x;
  const int lane = t & 63;
  const int w = t >> 6;             // 0..3
  const int l15 = lane & 15, lg = lane >> 4;
  const int xorv = (l15 & 7) << 4;

  const int lid = blockIdx.x;       // 0..1023
  const int xcd = lid & 7;
  const int m = lid >> 3;           // 0..127
  const int bh = (m & 3) * 8 + xcd; // 0..31
  const int qt = 31 - (m >> 2);     // 0..31, heavy first
  const int b = bh >> 4, h = bh & 15;
  const int q0 = qt * 64;
  const int qrow = q0 + w * 16;     // wave's 16 q-rows
  const int nkt = qt + 1;           // k-tiles of 64 (block-uniform)

  const size_t RS = 3 * CDIM;
  const u16* Qp  = QKV + (size_t)(b * TSEQ) * RS + h * DHEAD;
  const u16* Kp  = Qp + CDIM;
  const u16* Vgp = Vt + (size_t)(b * NHEAD + h) * DHEAD * TSEQ;
  char* PwB = (char*)&Ps[w * 16 * 64];

  u16x8 qf[2];
#pragma unroll
  for (int c = 0; c < 2; ++c)
    qf[c] = *(const u16x8*)(&Qp[(size_t)(qrow + l15) * RS + c * 32 + lg * 8]);

  f32x4 acc[4];
#pragma unroll
  for (int g = 0; g < 4; ++g) acc[g] = f32x4{0.f, 0.f, 0.f, 0.f};
  float m_run = -3e38f, l_run = 0.f;

  const int sr = t >> 2;            // 0..63
  const int c2 = (t & 3) * 2;       // chunk pair 0,2,4,6
  const int swA0 = sr * 128 + ((c2 * 16) ^ ((sr & 7) << 4));
  const int swA1 = sr * 128 + (((c2 + 1) * 16) ^ ((sr & 7) << 4));

  u16x8 kreg0 = *(const u16x8*)(&Kp[(size_t)sr * RS + c2 * 8]);
  u16x8 kreg1 = *(const u16x8*)(&Kp[(size_t)sr * RS + c2 * 8 + 8]);
  u16x8 vreg0 = *(const u16x8*)(&Vgp[(size_t)sr * TSEQ + c2 * 8]);
  u16x8 vreg1 = *(const u16x8*)(&Vgp[(size_t)sr * TSEQ + c2 * 8 + 8]);
  *(u16x8*)((char*)Ks[0] + swA0) = kreg0;
  *(u16x8*)((char*)Ks[0] + swA1) = kreg1;
  *(u16x8*)((char*)Vs[0] + swA0) = vreg0;
  *(u16x8*)((char*)Vs[0] + swA1) = vreg1;
  if (nkt > 1) {
    kreg0 = *(const u16x8*)(&Kp[(size_t)(64 + sr) * RS + c2 * 8]);
    kreg1 = *(const u16x8*)(&Kp[(size_t)(64 + sr) * RS + c2 * 8 + 8]);
    vreg0 = *(const u16x8*)(&Vgp[(size_t)sr * TSEQ + 64 + c2 * 8]);
    vreg1 = *(const u16x8*)(&Vgp[(size_t)sr * TSEQ + 64 + c2 * 8 + 8]);
  }
  __syncthreads();

  f32x4 sfr[4];
#pragma unroll
  for (int f = 0; f < 4; ++f) {
    const char* rowp = (char*)Ks[0] + (f * 16 + l15) * 128;
    u16x8 k0 = *(const u16x8*)(rowp + ((lg * 16) ^ xorv));
    u16x8 k1 = *(const u16x8*)(rowp + ((64 + lg * 16) ^ xorv));
    f32x4 s = mfma_bf16(k0, qf[0], f32x4{0.f, 0.f, 0.f, 0.f});
    sfr[f] = mfma_bf16(k1, qf[1], s);
  }

  for (int kb = 0; kb < nkt; ++kb) {
    const int p = kb & 1;
    char* VsB = (char*)Vs[p];

    if (kb + 1 < nkt) {
      *(u16x8*)((char*)Ks[p ^ 1] + swA0) = kreg0;
      *(u16x8*)((char*)Ks[p ^ 1] + swA1) = kreg1;
      *(u16x8*)((char*)Vs[p ^ 1] + swA0) = vreg0;
      *(u16x8*)((char*)Vs[p ^ 1] + swA1) = vreg1;
    }
    if (kb + 2 < nkt) {
      kreg0 = *(const u16x8*)(&Kp[(size_t)((kb + 2) * 64 + sr) * RS + c2 * 8]);
      kreg1 = *(const u16x8*)(&Kp[(size_t)((kb + 2) * 64 + sr) * RS + c2 * 8 + 8]);
      vreg0 = *(const u16x8*)(&Vgp[(size_t)sr * TSEQ + (kb + 2) * 64 + c2 * 8]);
      vreg1 = *(const u16x8*)(&Vgp[(size_t)sr * TSEQ + (kb + 2) * 64 + c2 * 8 + 8]);
    }
    __syncthreads();  // buf[p^1]=kb+1 ready; buf[p] (V of kb) still intact

    f32x4 snx[4];
    if (kb + 1 < nkt) {
      __builtin_amdgcn_s_setprio(1);
#pragma unroll
      for (int f = 0; f < 4; ++f) {
        const char* rowp = (char*)Ks[p ^ 1] + (f * 16 + l15) * 128;
        u16x8 k0 = *(const u16x8*)(rowp + ((lg * 16) ^ xorv));
        u16x8 k1 = *(const u16x8*)(rowp + ((64 + lg * 16) ^ xorv));
        f32x4 s = mfma_bf16(k0, qf[0], f32x4{0.f, 0.f, 0.f, 0.f});
        snx[f] = mfma_bf16(k1, qf[1], s);
      }
      __builtin_amdgcn_s_setprio(0);
    }

    if (kb * 64 + 63 > qrow) {
      const int q_abs = qrow + l15;
#pragma unroll
      for (int f = 0; f < 4; ++f) {
        const int kbase = kb * 64 + f * 16 + lg * 4;
#pragma unroll
        for (int r = 0; r < 4; ++r)
          if (kbase + r > q_abs) sfr[f][r] = -1e9f;
      }
    }

    float t0 = max3f(sfr[0][0], sfr[0][1], sfr[0][2]);
    float t1 = max3f(sfr[0][3], sfr[1][0], sfr[1][1]);
    float t2 = max3f(sfr[1][2], sfr[1][3], sfr[2][0]);
    float t3 = max3f(sfr[2][1], sfr[2][2], sfr[2][3]);
    float t4 = max3f(sfr[3][0], sfr[3][1], sfr[3][2]);
    float mx = fmaxf(max3f(t0, t1, t2), max3f(t3, t4, sfr[3][3]));

    if (__any(mx > m_run + 8.f)) {
      float gm = mx;
      gm = fmaxf(gm, __shfl_xor(gm, 16));
      gm = fmaxf(gm, __shfl_xor(gm, 32));
      float mnew = fmaxf(m_run, gm);
      float fac = exp2f(m_run - mnew);
      m_run = mnew;
      l_run *= fac;
#pragma unroll
      for (int g = 0; g < 4; ++g) acc[g] *= fac;
    }

    {
      char* pb = PwB + l15 * 128;
      float ls = 0.f;
#pragma unroll
      for (int f = 0; f < 4; ++f) {
        float p0 = exp2f(sfr[f][0] - m_run);
        float p1 = exp2f(sfr[f][1] - m_run);
        float p2 = exp2f(sfr[f][2] - m_run);
        float p3 = exp2f(sfr[f][3] - m_run);
        ls += (p0 + p1) + (p2 + p3);
        const int boff = (f * 32 + lg * 8) ^ xorv;  // 8B-aligned
        *(uint2*)(pb + boff) = make_uint2(pack2bf(p0, p1), pack2bf(p2, p3));
      }
      l_run += ls;
    }

    __builtin_amdgcn_s_setprio(1);
#pragma unroll
    for (int c = 0; c < 2; ++c) {
      const int coff = (c * 64 + lg * 16) ^ xorv;
      u16x8 pf = *(const u16x8*)(PwB + l15 * 128 + coff);
#pragma unroll
      for (int g = 0; g < 4; ++g) {
        u16x8 vf = *(const u16x8*)(VsB + (g * 16 + l15) * 128 + coff);
        acc[g] = mfma_bf16(vf, pf, acc[g]);
      }
    }
    __builtin_amdgcn_s_setprio(0);

    __syncthreads();

#pragma unroll
    for (int f = 0; f < 4; ++f) sfr[f] = snx[f];
  }

  float lt = l_run;
  lt += __shfl_xor(lt, 16);
  lt += __shfl_xor(lt, 32);
  float inv = 1.f / lt;
  {
    char* pb = PwB + l15 * 128;
#pragma unroll
    for (int g = 0; g < 4; ++g) {
      const int boff = (g * 32 + lg * 8) ^ xorv;
      *(uint2*)(pb + boff) = make_uint2(pack2bf(acc[g][0] * inv, acc[g][1] * inv),
                                        pack2bf(acc[g][2] * inv, acc[g][3] * inv));
    }
  }
#pragma unroll
  for (int i = 0; i < 2; ++i) {
    const int rl = i * 8 + (lane >> 3);  // 0..15
    const int ch = lane & 7;
    u16x8 vv = *(const u16x8*)(PwB + rl * 128 + ((ch * 16) ^ ((rl & 7) << 4)));
    *(u16x8*)(&O[(size_t)(b * TSEQ + qrow + rl) * CDIM + h * DHEAD + ch * 8]) = vv;
  }
}

// ---------------- launch ----------------

extern "C" void kernel_launch(void* const* d_in, const int* in_sizes, int n_in,
                              void* d_out, int out_size, void* d_ws, size_t ws_size,
                              hipStream_t stream) {
  const float* x  = (const float*)d_in[0];
  const float* wq = (const float*)d_in[1];
  const float* bq = (const float*)d_in[2];
  const float* wk = (const float*)d_in[3];
  const float* bk = (const float*)d_in[4];
  const float* wv = (const float*)d_in[5];
  const float* bv = (const float*)d_in[6];
  const float* wo = (const float*)d_in[7];
  const float* bo = (const float*)d_in[8];
  float* out = (float*)d_out;

  char* ws = (char*)d_ws;
  u16*  xb      = (u16*)(ws);                 // 8MB; dead after QKV GEMM
  u16*  Vtg     = (u16*)(ws);                 // aliases xb (written after)
  u16*  wqkvT   = (u16*)(ws + (8ll << 20));
  u16*  woT     = (u16*)(ws + (14ll << 20));
  u16*  QKV     = (u16*)(ws + (16ll << 20));
  u16*  Obuf    = (u16*)(ws + (40ll << 20));
  float* biasqkv = (float*)(ws + (48ll << 20));

  cast_x_kernel<<<(NROWS * CDIM / 4 + 255) / 256, 256, 0, stream>>>(x, xb, NROWS * CDIM / 4);
  {
    dim3 g(CDIM / 32, CDIM / 32, 4), blk(32, 8);
    transpose_cast_kernel<<<g, blk, 0, stream>>>(wq, wk, wv, wo, wqkvT, woT);
  }
  bias_concat_kernel<<<12, 256, 0, stream>>>(bq, bk, bv, biasqkv);
  gemm_bt_kernel<u16><<<(NROWS / 128) * ((3 * CDIM) / 128), 256, 0, stream>>>(
      xb, wqkvT, biasqkv, QKV, NROWS, 3 * CDIM, CDIM, (3 * CDIM) / 128);
  {
    dim3 g(TSEQ / 32, DHEAD / 32, BATCH * NHEAD), blk(32, 8);
    vtrans_kernel<<<g, blk, 0, stream>>>(QKV, Vtg);
  }
  attn_kernel<<<1024, 256, 0, stream>>>(QKV, Vtg, Obuf);
  gemm_bt_kernel<float><<<(NROWS / 128) * (CDIM / 128), 256, 0, stream>>>(
      Obuf, woT, bo, out, NROWS, CDIM, CDIM, CDIM / 128);
}